// Round 11
// baseline (995.756 us; speedup 1.0000x reference)
//
#include <hip/hip_runtime.h>
#include <stdint.h>

#define NB 8
#define NPTS 4096
#define NS 1024
#define NK 32
#define NROWS (NB*NS*NK)   // 262144
#define R2 0.04f
#define NCOPY 32           // atomic spreading copies for stats accum

typedef __attribute__((ext_vector_type(8))) short bf16x8;   // 8 bf16 in 4 VGPRs
typedef __attribute__((ext_vector_type(4))) float f32x4;    // MFMA 16x16 accumulator
typedef __attribute__((ext_vector_type(2))) float f32x2;    // packed fp32 (v_pk_*)

__device__ __forceinline__ float bf2f(uint16_t u){
    uint32_t v = ((uint32_t)u) << 16;
    return __uint_as_float(v);
}
__device__ __forceinline__ uint16_t f2bf(float f){
    uint32_t u = __float_as_uint(f);
    uint32_t r = (u + 0x7FFFu + ((u >> 16) & 1u)) >> 16;
    return (uint16_t)r;
}
__device__ __forceinline__ bf16x8 load_bf8(const uint16_t* p){
    return *reinterpret_cast<const bf16x8*>(p);
}

// float max with DPP-moved partner (VALU pipe). bound_ctrl=true fills 0.0f:
// safe — fill can never exceed the true wave max (distances >= 0), and the
// winning INDEX comes from ballot, not from the DPP value.
#define DPPMAXF(v, ctrl, rmask)                                                \
    {                                                                          \
        float _o = __uint_as_float((uint32_t)__builtin_amdgcn_update_dpp(      \
            0, (int)__float_as_uint(v), (ctrl), (rmask), 0xf, true));          \
        v = fmaxf(v, _o);                                                      \
    }

// ---------------------------------------------------------------- FPS
// 256 thr x FT=16, pk-f32 distance math (r10, proven 582 us). This round:
// serial-tail cut — (1) argmax select chain removed from the distance loop
// (fmax tree for bestd; post-loop equality mask + ctz gives smallest-j
// argmax, exact since fmax returns an operand bitwise); (2) float DPP wave
// max + ballot owner-find replaces the 64-bit DPP key chain (12 vs 30
// dependent inst). Blocked layout => lane order = index order => first
// ballot lane + ctz(mask) = smallest global index — identical tiebreak.
// Owner writes the same (dist<<32)|~idx key, so cross-wave combine is
// unchanged and bit-exact. DO NOT TOUCH the distance math (contract(off),
// a+(-c) == a-c IEEE; verified r2-r10).
// r5 lesson: no coord-carry / register-indexed fetch on the serial path.
// r9 lesson: 256thr/FT16 is the issue-optimal split.
#define FT 16
__global__ __launch_bounds__(256) void fps_kernel(const float* __restrict__ xyz,
                                                  float* __restrict__ out_newxyz){
    __shared__ float LX[NPTS], LY[NPTS], LZ[NPTS];
    __shared__ float4 SC[NS];
    __shared__ alignas(16) unsigned long long cand[2][4];
    const int b = blockIdx.x, t = threadIdx.x;
    const float* base = xyz + (size_t)b * (NPTS*3);
    f32x2 px2[FT/2], py2[FT/2], pz2[FT/2], pd2[FT/2];
#pragma unroll
    for (int j = 0; j < FT/2; ++j){
        int i = t*FT + 2*j;
        float x0 = base[i*3+0], y0 = base[i*3+1], z0 = base[i*3+2];
        float x1 = base[i*3+3], y1 = base[i*3+4], z1 = base[i*3+5];
        px2[j] = (f32x2){x0, x1};
        py2[j] = (f32x2){y0, y1};
        pz2[j] = (f32x2){z0, z1};
        pd2[j] = (f32x2){1e10f, 1e10f};
        LX[i]=x0; LY[i]=y0; LZ[i]=z0;
        LX[i+1]=x1; LY[i+1]=y1; LZ[i+1]=z1;
    }
    __syncthreads();
    int cur = 0;
    const int wave = t >> 6, lane = t & 63;
    for (int s = 0; s < NS; ++s){
        float cx = LX[cur], cy = LY[cur], cz = LZ[cur];
        if (t == 0) SC[s] = make_float4(cx, cy, cz, 0.f);
        f32x2 ncx = (f32x2){-cx, -cx};
        f32x2 ncy = (f32x2){-cy, -cy};
        f32x2 ncz = (f32x2){-cz, -cz};
        float bestd = -1.0f;
#pragma unroll
        for (int j = 0; j < FT/2; ++j){
            f32x2 d2;
            {
#pragma clang fp contract(off)
                f32x2 dx = px2[j] + ncx;       // pk_add; == px - cx bit-exact
                f32x2 dy = py2[j] + ncy;
                f32x2 dz = pz2[j] + ncz;
                f32x2 xx = dx*dx, yy = dy*dy, zz = dz*dz;   // pk_mul
                d2 = (xx + yy) + zz;                        // pk_add x2
            }
            f32x2 nd;
            nd.x = fminf(pd2[j].x, d2.x);
            nd.y = fminf(pd2[j].y, d2.y);
            pd2[j] = nd;
            bestd = fmaxf(bestd, fmaxf(nd.x, nd.y));   // max3-eligible tree
        }
        // local argmax: smallest j with pd==bestd (fmax returns operand exactly)
        uint32_t mask = 0;
#pragma unroll
        for (int j = 0; j < FT/2; ++j){
            if (pd2[j].x == bestd) mask |= (1u << (2*j));
            if (pd2[j].y == bestd) mask |= (1u << (2*j+1));
        }
        int besti = t*FT + __builtin_ctz(mask);
        // wave float max via DPP (cheap chain) -> lane 63
        float wmv = bestd;
        DPPMAXF(wmv, 0x111, 0xf);   // row_shr:1
        DPPMAXF(wmv, 0x112, 0xf);   // row_shr:2
        DPPMAXF(wmv, 0x114, 0xf);   // row_shr:4
        DPPMAXF(wmv, 0x118, 0xf);   // row_shr:8
        DPPMAXF(wmv, 0x142, 0xa);   // row_bcast:15 -> rows 1,3
        DPPMAXF(wmv, 0x143, 0xc);   // row_bcast:31 -> rows 2,3
        float wm = __uint_as_float((uint32_t)__builtin_amdgcn_readlane(
            (int)__float_as_uint(wmv), 63));
        // owner = first lane achieving wm (lane order == index order)
        unsigned long long bal = __ballot(bestd == wm);
        int owner = __ffsll(bal) - 1;
        int p = s & 1;
        if (lane == owner){
            cand[p][wave] =
                (((unsigned long long)__float_as_uint(bestd)) << 32) |
                (unsigned long long)(~(unsigned)besti);
        }
        __syncthreads();
        ulonglong2 c01 = *reinterpret_cast<const ulonglong2*>(&cand[p][0]);
        ulonglong2 c23 = *reinterpret_cast<const ulonglong2*>(&cand[p][2]);
        unsigned long long m01 = (c01.x > c01.y) ? c01.x : c01.y;
        unsigned long long m23 = (c23.x > c23.y) ? c23.x : c23.y;
        unsigned long long km  = (m01 > m23) ? m01 : m23;
        cur = (int)(~(uint32_t)km);
    }
    __syncthreads();
    for (int i = t; i < NS; i += 256){
        float4 c = SC[i];
        float* o = out_newxyz + ((size_t)b*NS + i)*3;
        o[0] = c.x; o[1] = c.y; o[2] = c.z;
    }
}

// ---------------------------------------------------------------- query ball
// UNCHANGED (verified).
__global__ __launch_bounds__(256) void qball_kernel(const float* __restrict__ xyz,
                                                    const float* __restrict__ newxyz,
                                                    int* __restrict__ idx_out){
    int gid = blockIdx.x*256 + threadIdx.x;
    int w = gid >> 6, lane = gid & 63;
    int b = w >> 10;
    const float* q = newxyz + (size_t)w*3;
    float qx = q[0], qy = q[1], qz = q[2];
    float qn = qx*qx;
    qn = fmaf(qy, qy, qn);
    qn = fmaf(qz, qz, qn);
    const float* base = xyz + (size_t)b * (NPTS*3);
    int cnt = 0, first = 0;
    for (int c0 = 0; c0 < NPTS; c0 += 64){
        int i = c0 + lane;
        float x = base[i*3+0], y = base[i*3+1], z = base[i*3+2];
        float xn = x*x;
        xn = fmaf(y, y, xn);
        xn = fmaf(z, z, xn);
        float dot = qx*x;
        dot = fmaf(qy, y, dot);
        dot = fmaf(qz, z, dot);
        float d;
        {
#pragma clang fp contract(off)
            d = -2.0f * dot;
            d = d + qn;
            d = d + xn;
        }
        bool in = !(d > R2);
        unsigned long long m = __ballot(in);
        if (in){
            int rank = __popcll(m & ((1ull << lane) - 1ull));
            int pos = cnt + rank;
            if (pos < NK) idx_out[(size_t)w*NK + pos] = i;
        }
        if (cnt == 0 && m) first = c0 + (__ffsll((unsigned long long)m) - 1);
        cnt += __popcll(m);
        if (cnt >= NK) break;
    }
    if (cnt < NK){
        for (int p = cnt + lane; p < NK; p += 64) idx_out[(size_t)w*NK + p] = first;
    }
}

// ---------------------------------------------------------------- weight prep (fp32 -> bf16) + accum zeroing
__global__ void prep_kernel(const float* __restrict__ w0, const float* __restrict__ w1,
                            const float* __restrict__ w2, uint16_t* __restrict__ w0b,
                            uint16_t* __restrict__ w1b, uint16_t* __restrict__ w2b,
                            double* __restrict__ accumAll){
    int t = blockIdx.x*256 + threadIdx.x;
    int stride = gridDim.x*256;
    for (int i = t; i < 3*NCOPY*256; i += stride) accumAll[i] = 0.0;
    for (int i = t; i < 64*96; i += stride){
        int n = i/96, c = i%96;
        w0b[i] = (c < 67) ? f2bf(w0[n*67 + c]) : (uint16_t)0;
    }
    for (int i = t; i < 64*64; i += stride)  w1b[i] = f2bf(w1[i]);
    for (int i = t; i < 128*64; i += stride) w2b[i] = f2bf(w2[i]);
}

// ---------------------------------------------------------------- layer 0: gather + GEMM 262144 x 96 -> 64 (MFMA) + fused stats
__global__ __launch_bounds__(256) void layer0_mfma(const float* __restrict__ xyz,
                                                   const float* __restrict__ pts,
                                                   const int* __restrict__ idx,
                                                   const float* __restrict__ newxyz,
                                                   const uint16_t* __restrict__ w0b,
                                                   const float* __restrict__ b0,
                                                   uint16_t* __restrict__ z0,
                                                   double* __restrict__ accumOut){
    __shared__ float S_s[16][64], S_q[16][64];
    const int wave = threadIdx.x >> 6, lane = threadIdx.x & 63;
    const int q = lane >> 4, l16 = lane & 15;
    const int r0 = blockIdx.x*64 + wave*16;
    const int row = r0 + l16;
    const int b = row >> 15;
    const int bs = row >> 5;
    const int id = idx[row];
    const float* prow = pts + (((size_t)b << 12) + id)*64;
    const float* xr   = xyz + (((size_t)b << 12) + id)*3;
    const float* qr   = newxyz + (size_t)bs*3;
    float d0 = xr[0]-qr[0], d1 = xr[1]-qr[1], d2 = xr[2]-qr[2];

    bf16x8 Bf[4][3];
#pragma unroll
    for (int nt = 0; nt < 4; ++nt)
#pragma unroll
        for (int s = 0; s < 3; ++s)
            Bf[nt][s] = load_bf8(w0b + (nt*16 + l16)*96 + s*32 + q*8);

    f32x4 acc[4];
#pragma unroll
    for (int nt = 0; nt < 4; ++nt) acc[nt] = (f32x4){0.f,0.f,0.f,0.f};

#pragma unroll
    for (int s = 0; s < 3; ++s){
        const int k0 = s*32 + q*8;
        bf16x8 a;
#pragma unroll
        for (int j = 0; j < 8; ++j){
            int k = k0 + j;
            float v = (k < 3) ? ((k == 0) ? d0 : ((k == 1) ? d1 : d2))
                              : ((k < 67) ? prow[k-3] : 0.f);
            a[j] = (short)f2bf(v);
        }
#pragma unroll
        for (int nt = 0; nt < 4; ++nt)
            acc[nt] = __builtin_amdgcn_mfma_f32_16x16x32_bf16(a, Bf[nt][s], acc[nt], 0, 0, 0);
    }
    // C/D: col=lane&15, row=quad*4+reg. Epilogue: bias, store, f32 stats partials.
#pragma unroll
    for (int nt = 0; nt < 4; ++nt){
        int c = nt*16 + l16;
        float bb = b0[c];
        float sps = 0.f, spq = 0.f;
#pragma unroll
        for (int reg = 0; reg < 4; ++reg){
            int rr = r0 + q*4 + reg;
            float h = acc[nt][reg] + bb;
            sps += h;
            spq = fmaf(h, h, spq);
            z0[(size_t)rr*64 + c] = f2bf(h);
        }
        S_s[wave*4 + q][c] = sps;
        S_q[wave*4 + q][c] = spq;
    }
    __syncthreads();
    int t = threadIdx.x;
    if (t < 64){
        double ss = 0.0, sq = 0.0;
#pragma unroll
        for (int i = 0; i < 16; ++i){ ss += (double)S_s[i][t]; sq += (double)S_q[i][t]; }
        int cp = blockIdx.x & (NCOPY-1);
        atomicAdd(&accumOut[cp*256 + t], ss);
        atomicAdd(&accumOut[cp*256 + 128 + t], sq);
    }
}

// ---------------------------------------------------------------- layer 1: inline BN-param + BN+relu+GEMM K=64 + fused stats
__global__ __launch_bounds__(256) void layer1_mfma(const uint16_t* __restrict__ zin,
                                                   const double* __restrict__ accumIn,
                                                   const float* __restrict__ g,
                                                   const float* __restrict__ be,
                                                   const uint16_t* __restrict__ wb,
                                                   const float* __restrict__ bias,
                                                   uint16_t* __restrict__ zout,
                                                   double* __restrict__ accumOut){
    constexpr int NT = 4;
    __shared__ float sc_l[64], sh_l[64];
    __shared__ float S_s[16][64], S_q[16][64];
    const int t = threadIdx.x;
    if (t < 64){
        double s = 0.0, qq = 0.0;
#pragma unroll
        for (int cp = 0; cp < NCOPY; ++cp){
            s  += accumIn[cp*256 + t];
            qq += accumIn[cp*256 + 128 + t];
        }
        double mean = s / (double)NROWS;
        double var  = qq / (double)NROWS - mean*mean;
        double rs = 1.0 / sqrt(var + 1e-5);
        double scv = (double)g[t] * rs;
        sc_l[t] = (float)scv;
        sh_l[t] = (float)((double)be[t] - mean*scv);
    }
    __syncthreads();

    const int wave = t >> 6, lane = t & 63;
    const int q = lane >> 4, l16 = lane & 15;
    const int r0 = blockIdx.x*64 + wave*16;

    bf16x8 Bf[NT][2];
#pragma unroll
    for (int nt = 0; nt < NT; ++nt)
#pragma unroll
        for (int s = 0; s < 2; ++s)
            Bf[nt][s] = load_bf8(wb + (nt*16 + l16)*64 + s*32 + q*8);

    float sc[2][8], sh[2][8];
#pragma unroll
    for (int s = 0; s < 2; ++s)
#pragma unroll
        for (int j = 0; j < 8; ++j){
            sc[s][j] = sc_l[s*32 + q*8 + j];
            sh[s][j] = sh_l[s*32 + q*8 + j];
        }

    f32x4 acc[NT];
#pragma unroll
    for (int nt = 0; nt < NT; ++nt) acc[nt] = (f32x4){0.f,0.f,0.f,0.f};

    const uint16_t* zr = zin + (size_t)(r0 + l16)*64;
#pragma unroll
    for (int s = 0; s < 2; ++s){
        uint4 u = *reinterpret_cast<const uint4*>(zr + s*32 + q*8);
        float h[8];
        h[0] = bf2f((uint16_t)(u.x & 0xFFFF)); h[1] = bf2f((uint16_t)(u.x >> 16));
        h[2] = bf2f((uint16_t)(u.y & 0xFFFF)); h[3] = bf2f((uint16_t)(u.y >> 16));
        h[4] = bf2f((uint16_t)(u.z & 0xFFFF)); h[5] = bf2f((uint16_t)(u.z >> 16));
        h[6] = bf2f((uint16_t)(u.w & 0xFFFF)); h[7] = bf2f((uint16_t)(u.w >> 16));
        bf16x8 a;
#pragma unroll
        for (int j = 0; j < 8; ++j){
            float v = fmaxf(fmaf(h[j], sc[s][j], sh[s][j]), 0.f);
            a[j] = (short)f2bf(v);
        }
#pragma unroll
        for (int nt = 0; nt < NT; ++nt)
            acc[nt] = __builtin_amdgcn_mfma_f32_16x16x32_bf16(a, Bf[nt][s], acc[nt], 0, 0, 0);
    }
#pragma unroll
    for (int nt = 0; nt < NT; ++nt){
        int c = nt*16 + l16;
        float bb = bias[c];
        float sps = 0.f, spq = 0.f;
#pragma unroll
        for (int reg = 0; reg < 4; ++reg){
            int rr = r0 + q*4 + reg;
            float h = acc[nt][reg] + bb;
            sps += h;
            spq = fmaf(h, h, spq);
            zout[(size_t)rr*64 + c] = f2bf(h);
        }
        S_s[wave*4 + q][c] = sps;
        S_q[wave*4 + q][c] = spq;
    }
    __syncthreads();
    if (t < 64){
        double ss = 0.0, sq = 0.0;
#pragma unroll
        for (int i = 0; i < 16; ++i){ ss += (double)S_s[i][t]; sq += (double)S_q[i][t]; }
        int cp = blockIdx.x & (NCOPY-1);
        atomicAdd(&accumOut[cp*256 + t], ss);
        atomicAdd(&accumOut[cp*256 + 128 + t], sq);
    }
}

// ---------------------------------------------------------------- layer 2: BN+relu+GEMM K=64 -> 128 + fused stats + fused max/min POOLING
// Pooling in f32 pre-BN space; final kernel applies BN and picks max/min by
// sign(scale). z2 (67 MB x2 traffic) is never materialized.
__global__ __launch_bounds__(256) void layer2_mfma(const uint16_t* __restrict__ zin,
                                                   const double* __restrict__ accumIn,
                                                   const float* __restrict__ g,
                                                   const float* __restrict__ be,
                                                   const uint16_t* __restrict__ wb,
                                                   const float* __restrict__ bias,
                                                   float2* __restrict__ pool,
                                                   double* __restrict__ accumOut){
    constexpr int NT = 8;
    __shared__ float sc_l[64], sh_l[64];
    __shared__ float S_s[16][128], S_q[16][128];
    __shared__ float P_mx[16][128], P_mn[16][128];
    const int t = threadIdx.x;
    if (t < 64){
        double s = 0.0, qq = 0.0;
#pragma unroll
        for (int cp = 0; cp < NCOPY; ++cp){
            s  += accumIn[cp*256 + t];
            qq += accumIn[cp*256 + 128 + t];
        }
        double mean = s / (double)NROWS;
        double var  = qq / (double)NROWS - mean*mean;
        double rs = 1.0 / sqrt(var + 1e-5);
        double scv = (double)g[t] * rs;
        sc_l[t] = (float)scv;
        sh_l[t] = (float)((double)be[t] - mean*scv);
    }
    __syncthreads();

    const int wave = t >> 6, lane = t & 63;
    const int q = lane >> 4, l16 = lane & 15;
    const int r0 = blockIdx.x*64 + wave*16;

    bf16x8 Bf[NT][2];
#pragma unroll
    for (int nt = 0; nt < NT; ++nt)
#pragma unroll
        for (int s = 0; s < 2; ++s)
            Bf[nt][s] = load_bf8(wb + (nt*16 + l16)*64 + s*32 + q*8);

    float sc[2][8], sh[2][8];
#pragma unroll
    for (int s = 0; s < 2; ++s)
#pragma unroll
        for (int j = 0; j < 8; ++j){
            sc[s][j] = sc_l[s*32 + q*8 + j];
            sh[s][j] = sh_l[s*32 + q*8 + j];
        }

    f32x4 acc[NT];
#pragma unroll
    for (int nt = 0; nt < NT; ++nt) acc[nt] = (f32x4){0.f,0.f,0.f,0.f};

    const uint16_t* zr = zin + (size_t)(r0 + l16)*64;
#pragma unroll
    for (int s = 0; s < 2; ++s){
        uint4 u = *reinterpret_cast<const uint4*>(zr + s*32 + q*8);
        float h[8];
        h[0] = bf2f((uint16_t)(u.x & 0xFFFF)); h[1] = bf2f((uint16_t)(u.x >> 16));
        h[2] = bf2f((uint16_t)(u.y & 0xFFFF)); h[3] = bf2f((uint16_t)(u.y >> 16));
        h[4] = bf2f((uint16_t)(u.z & 0xFFFF)); h[5] = bf2f((uint16_t)(u.z >> 16));
        h[6] = bf2f((uint16_t)(u.w & 0xFFFF)); h[7] = bf2f((uint16_t)(u.w >> 16));
        bf16x8 a;
#pragma unroll
        for (int j = 0; j < 8; ++j){
            float v = fmaxf(fmaf(h[j], sc[s][j], sh[s][j]), 0.f);
            a[j] = (short)f2bf(v);
        }
#pragma unroll
        for (int nt = 0; nt < NT; ++nt)
            acc[nt] = __builtin_amdgcn_mfma_f32_16x16x32_bf16(a, Bf[nt][s], acc[nt], 0, 0, 0);
    }
#pragma unroll
    for (int nt = 0; nt < NT; ++nt){
        int c = nt*16 + l16;
        float bb = bias[c];
        float sps = 0.f, spq = 0.f;
        float mx = -1e30f, mn = 1e30f;
#pragma unroll
        for (int reg = 0; reg < 4; ++reg){
            float h = acc[nt][reg] + bb;
            sps += h;
            spq = fmaf(h, h, spq);
            mx = fmaxf(mx, h);
            mn = fminf(mn, h);
        }
        S_s[wave*4 + q][c] = sps;
        S_q[wave*4 + q][c] = spq;
        P_mx[wave*4 + q][c] = mx;
        P_mn[wave*4 + q][c] = mn;
    }
    __syncthreads();
    if (t < 128){
        double ss = 0.0, sq = 0.0;
#pragma unroll
        for (int i = 0; i < 16; ++i){ ss += (double)S_s[i][t]; sq += (double)S_q[i][t]; }
        int cp = blockIdx.x & (NCOPY-1);
        atomicAdd(&accumOut[cp*256 + t], ss);
        atomicAdd(&accumOut[cp*256 + 128 + t], sq);
    }
    // pooling: block covers 2 groups of 32 rows (= 2 (b,s) cells)
    {
        int gidx = t >> 7;          // 0..1
        int c = t & 127;
        float mx = -1e30f, mn = 1e30f;
#pragma unroll
        for (int i = 0; i < 8; ++i){
            mx = fmaxf(mx, P_mx[gidx*8 + i][c]);
            mn = fminf(mn, P_mn[gidx*8 + i][c]);
        }
        pool[(size_t)(blockIdx.x*2 + gidx)*128 + c] = make_float2(mx, mn);
    }
}

// ---------------------------------------------------------------- final: inline BN-param + select max/min by sign(scale) + BN + relu + transpose
__global__ __launch_bounds__(256) void final_kernel(const float2* __restrict__ pool,
                                                    const double* __restrict__ accumIn,
                                                    const float* __restrict__ g,
                                                    const float* __restrict__ be,
                                                    float* __restrict__ out){
    __shared__ float sc_l[128], sh_l[128];
    const int t0 = threadIdx.x;
    if (t0 < 128){
        double s = 0.0, qq = 0.0;
#pragma unroll
        for (int cp = 0; cp < NCOPY; ++cp){
            s  += accumIn[cp*256 + t0];
            qq += accumIn[cp*256 + 128 + t0];
        }
        double mean = s / (double)NROWS;
        double var  = qq / (double)NROWS - mean*mean;
        double rs = 1.0 / sqrt(var + 1e-5);
        double scv = (double)g[t0] * rs;
        sc_l[t0] = (float)scv;
        sh_l[t0] = (float)((double)be[t0] - mean*scv);
    }
    __syncthreads();

    int t = blockIdx.x*256 + threadIdx.x;   // 1048576 == pool linear index
    int o = t & 127;
    int s = (t >> 7) & 1023;
    int b = t >> 17;
    float2 p = pool[t];
    float sc = sc_l[o], sh = sh_l[o];
    float zsel = (sc >= 0.f) ? p.x : p.y;
    float y = fmaxf(fmaf(zsel, sc, sh), 0.f);
    out[24576 + ((size_t)b << 17) + ((size_t)o << 10) + s] = y;
}

// ---------------------------------------------------------------- launch
extern "C" void kernel_launch(void* const* d_in, const int* in_sizes, int n_in,
                              void* d_out, int out_size, void* d_ws, size_t ws_size,
                              hipStream_t stream) {
    const float* xyz = (const float*)d_in[0];
    const float* pts = (const float*)d_in[1];
    const float* w0  = (const float*)d_in[2];
    const float* b0  = (const float*)d_in[3];
    const float* g0  = (const float*)d_in[4];
    const float* be0 = (const float*)d_in[5];
    const float* w1  = (const float*)d_in[6];
    const float* b1  = (const float*)d_in[7];
    const float* g1  = (const float*)d_in[8];
    const float* be1 = (const float*)d_in[9];
    const float* w2  = (const float*)d_in[10];
    const float* b2  = (const float*)d_in[11];
    const float* g2  = (const float*)d_in[12];
    const float* be2 = (const float*)d_in[13];
    float* out = (float*)d_out;

    char* ws = (char*)d_ws;
    // accum: 3 layers x NCOPY x 256 doubles = 196608 B
    double*   accum0 = (double*)(ws + 0);
    double*   accum1 = (double*)(ws + 65536);
    double*   accum2 = (double*)(ws + 131072);
    uint16_t* w0b    = (uint16_t*)(ws + 196608);    // 12288 B
    uint16_t* w1b    = (uint16_t*)(ws + 208896);    // 8192 B
    uint16_t* w2b    = (uint16_t*)(ws + 217088);    // 16384 B
    uint16_t* z0     = (uint16_t*)(ws + 262144);    // 33554432 B
    uint16_t* z1     = (uint16_t*)(ws + 33816576);  // 33554432 B
    float2*   pool   = (float2*)  (ws + 67371008);  // 8388608 B
    int*      idx    = (int*)     (ws + 75759616);  // 1048576 B -> ends 76808192

    prep_kernel<<<32, 256, 0, stream>>>(w0, w1, w2, w0b, w1b, w2b, accum0);
    fps_kernel<<<NB, 256, 0, stream>>>(xyz, out);
    qball_kernel<<<2048, 256, 0, stream>>>(xyz, out, idx);
    layer0_mfma<<<4096, 256, 0, stream>>>(xyz, pts, idx, out, w0b, b0, z0, accum0);
    layer1_mfma<<<4096, 256, 0, stream>>>(z0, accum0, g0, be0, w1b, b1, z1, accum1);
    layer2_mfma<<<4096, 256, 0, stream>>>(z1, accum1, g1, be1, w2b, b2, pool, accum2);
    final_kernel<<<4096, 256, 0, stream>>>(pool, accum2, g2, be2, out);
}

// Round 12
// 845.726 us; speedup vs baseline: 1.1774x; 1.1774x over previous
//
#include <hip/hip_runtime.h>
#include <stdint.h>

#define NB 8
#define NPTS 4096
#define NS 1024
#define NK 32
#define NROWS (NB*NS*NK)   // 262144
#define R2 0.04f
#define NCOPY 32           // atomic spreading copies for stats accum

typedef __attribute__((ext_vector_type(8))) short bf16x8;   // 8 bf16 in 4 VGPRs
typedef __attribute__((ext_vector_type(4))) float f32x4;    // MFMA 16x16 accumulator
typedef __attribute__((ext_vector_type(2))) float f32x2;    // packed fp32 (v_pk_*)

__device__ __forceinline__ float bf2f(uint16_t u){
    uint32_t v = ((uint32_t)u) << 16;
    return __uint_as_float(v);
}
__device__ __forceinline__ uint16_t f2bf(float f){
    uint32_t u = __float_as_uint(f);
    uint32_t r = (u + 0x7FFFu + ((u >> 16) & 1u)) >> 16;
    return (uint16_t)r;
}
__device__ __forceinline__ bf16x8 load_bf8(const uint16_t* p){
    return *reinterpret_cast<const bf16x8*>(p);
}

// 64-bit max with a DPP-moved partner; masked-off / invalid lanes receive 0,
// which never wins (low word of a real key is ~idx >= 0xFFFFF000 != 0).
#define DPPMAX64(key, ctrl, rmask)                                             \
    {                                                                          \
        uint32_t _lo = (uint32_t)(key), _hi = (uint32_t)((key) >> 32);         \
        uint32_t _olo = (uint32_t)__builtin_amdgcn_update_dpp(                 \
            0, (int)_lo, (ctrl), (rmask), 0xf, true);                          \
        uint32_t _ohi = (uint32_t)__builtin_amdgcn_update_dpp(                 \
            0, (int)_hi, (ctrl), (rmask), 0xf, true);                          \
        unsigned long long _o = (((unsigned long long)_ohi) << 32) | _olo;     \
        key = (_o > (key)) ? _o : (key);                                       \
    }

// ---------------------------------------------------------------- FPS (+ fused prep on extra blocks)
// fps body is the r10 kernel VERBATIM (measured 582 us — best of 8 variants).
// Proven-regression list (do not retry): coord-carry cand (r5), float4 LDS
// coords (r8), 512 threads (r9), ballot owner-find / post-loop equality mask
// (r5, r11). Proven wins: DPP-VALU u64 reduce (r3), pk-f32 distance (r10).
// DO NOT TOUCH the distance math: contract(off), a+(-c) == a-c IEEE —
// selection is bit-exact vs reference (verified r2-r11).
// Blocks 8..39 run the old prep_kernel body (weights fp32->bf16 + accum
// zeroing) on otherwise-idle CUs; consumers launch after this kernel.
#define FT 16
__global__ __launch_bounds__(256) void fps_prep_kernel(const float* __restrict__ xyz,
                                                       float* __restrict__ out_newxyz,
                                                       const float* __restrict__ w0,
                                                       const float* __restrict__ w1,
                                                       const float* __restrict__ w2,
                                                       uint16_t* __restrict__ w0b,
                                                       uint16_t* __restrict__ w1b,
                                                       uint16_t* __restrict__ w2b,
                                                       double* __restrict__ accumAll){
    __shared__ float LX[NPTS], LY[NPTS], LZ[NPTS];
    __shared__ float4 SC[NS];
    __shared__ alignas(16) unsigned long long cand[2][4];
    if (blockIdx.x >= NB){
        // ---- prep path (blocks 8..39) ----
        int t = (blockIdx.x - NB)*256 + threadIdx.x;
        int stride = 32*256;
        for (int i = t; i < 3*NCOPY*256; i += stride) accumAll[i] = 0.0;
        for (int i = t; i < 64*96; i += stride){
            int n = i/96, c = i%96;
            w0b[i] = (c < 67) ? f2bf(w0[n*67 + c]) : (uint16_t)0;
        }
        for (int i = t; i < 64*64; i += stride)  w1b[i] = f2bf(w1[i]);
        for (int i = t; i < 128*64; i += stride) w2b[i] = f2bf(w2[i]);
        return;
    }
    // ---- fps path (blocks 0..7), r10 verbatim ----
    const int b = blockIdx.x, t = threadIdx.x;
    const float* base = xyz + (size_t)b * (NPTS*3);
    f32x2 px2[FT/2], py2[FT/2], pz2[FT/2], pd2[FT/2];
#pragma unroll
    for (int j = 0; j < FT/2; ++j){
        int i = t*FT + 2*j;
        float x0 = base[i*3+0], y0 = base[i*3+1], z0 = base[i*3+2];
        float x1 = base[i*3+3], y1 = base[i*3+4], z1 = base[i*3+5];
        px2[j] = (f32x2){x0, x1};
        py2[j] = (f32x2){y0, y1};
        pz2[j] = (f32x2){z0, z1};
        pd2[j] = (f32x2){1e10f, 1e10f};
        LX[i]=x0; LY[i]=y0; LZ[i]=z0;
        LX[i+1]=x1; LY[i+1]=y1; LZ[i+1]=z1;
    }
    __syncthreads();
    int cur = 0;
    const int wave = t >> 6, lane = t & 63;
    for (int s = 0; s < NS; ++s){
        float cx = LX[cur], cy = LY[cur], cz = LZ[cur];
        if (t == 0) SC[s] = make_float4(cx, cy, cz, 0.f);
        f32x2 ncx = (f32x2){-cx, -cx};
        f32x2 ncy = (f32x2){-cy, -cy};
        f32x2 ncz = (f32x2){-cz, -cz};
        float bestd = -1.0f; int besti = 0;
#pragma unroll
        for (int j = 0; j < FT/2; ++j){
            f32x2 d2;
            {
#pragma clang fp contract(off)
                f32x2 dx = px2[j] + ncx;       // pk_add; == px - cx bit-exact
                f32x2 dy = py2[j] + ncy;
                f32x2 dz = pz2[j] + ncz;
                f32x2 xx = dx*dx, yy = dy*dy, zz = dz*dz;   // pk_mul
                d2 = (xx + yy) + zz;                        // pk_add x2
            }
            f32x2 nd;
            nd.x = fminf(pd2[j].x, d2.x);
            nd.y = fminf(pd2[j].y, d2.y);
            pd2[j] = nd;
            if (nd.x > bestd){ bestd = nd.x; besti = t*FT + 2*j; }
            if (nd.y > bestd){ bestd = nd.y; besti = t*FT + 2*j + 1; }
        }
        unsigned long long key =
            (((unsigned long long)__float_as_uint(bestd)) << 32) |
            (unsigned long long)(~(unsigned)besti);
        DPPMAX64(key, 0x111, 0xf);   // row_shr:1
        DPPMAX64(key, 0x112, 0xf);   // row_shr:2
        DPPMAX64(key, 0x114, 0xf);   // row_shr:4
        DPPMAX64(key, 0x118, 0xf);   // row_shr:8
        DPPMAX64(key, 0x142, 0xa);   // row_bcast:15 -> rows 1,3
        DPPMAX64(key, 0x143, 0xc);   // row_bcast:31 -> rows 2,3
        int p = s & 1;
        if (lane == 63) cand[p][wave] = key;
        __syncthreads();
        ulonglong2 c01 = *reinterpret_cast<const ulonglong2*>(&cand[p][0]);
        ulonglong2 c23 = *reinterpret_cast<const ulonglong2*>(&cand[p][2]);
        unsigned long long m01 = (c01.x > c01.y) ? c01.x : c01.y;
        unsigned long long m23 = (c23.x > c23.y) ? c23.x : c23.y;
        unsigned long long km  = (m01 > m23) ? m01 : m23;
        cur = (int)(~(uint32_t)km);
    }
    __syncthreads();
    for (int i = t; i < NS; i += 256){
        float4 c = SC[i];
        float* o = out_newxyz + ((size_t)b*NS + i)*3;
        o[0] = c.x; o[1] = c.y; o[2] = c.z;
    }
}

// ---------------------------------------------------------------- query ball
// UNCHANGED (verified).
__global__ __launch_bounds__(256) void qball_kernel(const float* __restrict__ xyz,
                                                    const float* __restrict__ newxyz,
                                                    int* __restrict__ idx_out){
    int gid = blockIdx.x*256 + threadIdx.x;
    int w = gid >> 6, lane = gid & 63;
    int b = w >> 10;
    const float* q = newxyz + (size_t)w*3;
    float qx = q[0], qy = q[1], qz = q[2];
    float qn = qx*qx;
    qn = fmaf(qy, qy, qn);
    qn = fmaf(qz, qz, qn);
    const float* base = xyz + (size_t)b * (NPTS*3);
    int cnt = 0, first = 0;
    for (int c0 = 0; c0 < NPTS; c0 += 64){
        int i = c0 + lane;
        float x = base[i*3+0], y = base[i*3+1], z = base[i*3+2];
        float xn = x*x;
        xn = fmaf(y, y, xn);
        xn = fmaf(z, z, xn);
        float dot = qx*x;
        dot = fmaf(qy, y, dot);
        dot = fmaf(qz, z, dot);
        float d;
        {
#pragma clang fp contract(off)
            d = -2.0f * dot;
            d = d + qn;
            d = d + xn;
        }
        bool in = !(d > R2);
        unsigned long long m = __ballot(in);
        if (in){
            int rank = __popcll(m & ((1ull << lane) - 1ull));
            int pos = cnt + rank;
            if (pos < NK) idx_out[(size_t)w*NK + pos] = i;
        }
        if (cnt == 0 && m) first = c0 + (__ffsll((unsigned long long)m) - 1);
        cnt += __popcll(m);
        if (cnt >= NK) break;
    }
    if (cnt < NK){
        for (int p = cnt + lane; p < NK; p += 64) idx_out[(size_t)w*NK + p] = first;
    }
}

// ---------------------------------------------------------------- layer 0: gather + GEMM 262144 x 96 -> 64 (MFMA) + fused stats
__global__ __launch_bounds__(256) void layer0_mfma(const float* __restrict__ xyz,
                                                   const float* __restrict__ pts,
                                                   const int* __restrict__ idx,
                                                   const float* __restrict__ newxyz,
                                                   const uint16_t* __restrict__ w0b,
                                                   const float* __restrict__ b0,
                                                   uint16_t* __restrict__ z0,
                                                   double* __restrict__ accumOut){
    __shared__ float S_s[16][64], S_q[16][64];
    const int wave = threadIdx.x >> 6, lane = threadIdx.x & 63;
    const int q = lane >> 4, l16 = lane & 15;
    const int r0 = blockIdx.x*64 + wave*16;
    const int row = r0 + l16;
    const int b = row >> 15;
    const int bs = row >> 5;
    const int id = idx[row];
    const float* prow = pts + (((size_t)b << 12) + id)*64;
    const float* xr   = xyz + (((size_t)b << 12) + id)*3;
    const float* qr   = newxyz + (size_t)bs*3;
    float d0 = xr[0]-qr[0], d1 = xr[1]-qr[1], d2 = xr[2]-qr[2];

    bf16x8 Bf[4][3];
#pragma unroll
    for (int nt = 0; nt < 4; ++nt)
#pragma unroll
        for (int s = 0; s < 3; ++s)
            Bf[nt][s] = load_bf8(w0b + (nt*16 + l16)*96 + s*32 + q*8);

    f32x4 acc[4];
#pragma unroll
    for (int nt = 0; nt < 4; ++nt) acc[nt] = (f32x4){0.f,0.f,0.f,0.f};

#pragma unroll
    for (int s = 0; s < 3; ++s){
        const int k0 = s*32 + q*8;
        bf16x8 a;
#pragma unroll
        for (int j = 0; j < 8; ++j){
            int k = k0 + j;
            float v = (k < 3) ? ((k == 0) ? d0 : ((k == 1) ? d1 : d2))
                              : ((k < 67) ? prow[k-3] : 0.f);
            a[j] = (short)f2bf(v);
        }
#pragma unroll
        for (int nt = 0; nt < 4; ++nt)
            acc[nt] = __builtin_amdgcn_mfma_f32_16x16x32_bf16(a, Bf[nt][s], acc[nt], 0, 0, 0);
    }
    // C/D: col=lane&15, row=quad*4+reg. Epilogue: bias, store, f32 stats partials.
#pragma unroll
    for (int nt = 0; nt < 4; ++nt){
        int c = nt*16 + l16;
        float bb = b0[c];
        float sps = 0.f, spq = 0.f;
#pragma unroll
        for (int reg = 0; reg < 4; ++reg){
            int rr = r0 + q*4 + reg;
            float h = acc[nt][reg] + bb;
            sps += h;
            spq = fmaf(h, h, spq);
            z0[(size_t)rr*64 + c] = f2bf(h);
        }
        S_s[wave*4 + q][c] = sps;
        S_q[wave*4 + q][c] = spq;
    }
    __syncthreads();
    int t = threadIdx.x;
    if (t < 64){
        double ss = 0.0, sq = 0.0;
#pragma unroll
        for (int i = 0; i < 16; ++i){ ss += (double)S_s[i][t]; sq += (double)S_q[i][t]; }
        int cp = blockIdx.x & (NCOPY-1);
        atomicAdd(&accumOut[cp*256 + t], ss);
        atomicAdd(&accumOut[cp*256 + 128 + t], sq);
    }
}

// ---------------------------------------------------------------- layer 1: inline BN-param + BN+relu+GEMM K=64 + fused stats
__global__ __launch_bounds__(256) void layer1_mfma(const uint16_t* __restrict__ zin,
                                                   const double* __restrict__ accumIn,
                                                   const float* __restrict__ g,
                                                   const float* __restrict__ be,
                                                   const uint16_t* __restrict__ wb,
                                                   const float* __restrict__ bias,
                                                   uint16_t* __restrict__ zout,
                                                   double* __restrict__ accumOut){
    constexpr int NT = 4;
    __shared__ float sc_l[64], sh_l[64];
    __shared__ float S_s[16][64], S_q[16][64];
    const int t = threadIdx.x;
    if (t < 64){
        double s = 0.0, qq = 0.0;
#pragma unroll
        for (int cp = 0; cp < NCOPY; ++cp){
            s  += accumIn[cp*256 + t];
            qq += accumIn[cp*256 + 128 + t];
        }
        double mean = s / (double)NROWS;
        double var  = qq / (double)NROWS - mean*mean;
        double rs = 1.0 / sqrt(var + 1e-5);
        double scv = (double)g[t] * rs;
        sc_l[t] = (float)scv;
        sh_l[t] = (float)((double)be[t] - mean*scv);
    }
    __syncthreads();

    const int wave = t >> 6, lane = t & 63;
    const int q = lane >> 4, l16 = lane & 15;
    const int r0 = blockIdx.x*64 + wave*16;

    bf16x8 Bf[NT][2];
#pragma unroll
    for (int nt = 0; nt < NT; ++nt)
#pragma unroll
        for (int s = 0; s < 2; ++s)
            Bf[nt][s] = load_bf8(wb + (nt*16 + l16)*64 + s*32 + q*8);

    float sc[2][8], sh[2][8];
#pragma unroll
    for (int s = 0; s < 2; ++s)
#pragma unroll
        for (int j = 0; j < 8; ++j){
            sc[s][j] = sc_l[s*32 + q*8 + j];
            sh[s][j] = sh_l[s*32 + q*8 + j];
        }

    f32x4 acc[NT];
#pragma unroll
    for (int nt = 0; nt < NT; ++nt) acc[nt] = (f32x4){0.f,0.f,0.f,0.f};

    const uint16_t* zr = zin + (size_t)(r0 + l16)*64;
#pragma unroll
    for (int s = 0; s < 2; ++s){
        uint4 u = *reinterpret_cast<const uint4*>(zr + s*32 + q*8);
        float h[8];
        h[0] = bf2f((uint16_t)(u.x & 0xFFFF)); h[1] = bf2f((uint16_t)(u.x >> 16));
        h[2] = bf2f((uint16_t)(u.y & 0xFFFF)); h[3] = bf2f((uint16_t)(u.y >> 16));
        h[4] = bf2f((uint16_t)(u.z & 0xFFFF)); h[5] = bf2f((uint16_t)(u.z >> 16));
        h[6] = bf2f((uint16_t)(u.w & 0xFFFF)); h[7] = bf2f((uint16_t)(u.w >> 16));
        bf16x8 a;
#pragma unroll
        for (int j = 0; j < 8; ++j){
            float v = fmaxf(fmaf(h[j], sc[s][j], sh[s][j]), 0.f);
            a[j] = (short)f2bf(v);
        }
#pragma unroll
        for (int nt = 0; nt < NT; ++nt)
            acc[nt] = __builtin_amdgcn_mfma_f32_16x16x32_bf16(a, Bf[nt][s], acc[nt], 0, 0, 0);
    }
#pragma unroll
    for (int nt = 0; nt < NT; ++nt){
        int c = nt*16 + l16;
        float bb = bias[c];
        float sps = 0.f, spq = 0.f;
#pragma unroll
        for (int reg = 0; reg < 4; ++reg){
            int rr = r0 + q*4 + reg;
            float h = acc[nt][reg] + bb;
            sps += h;
            spq = fmaf(h, h, spq);
            zout[(size_t)rr*64 + c] = f2bf(h);
        }
        S_s[wave*4 + q][c] = sps;
        S_q[wave*4 + q][c] = spq;
    }
    __syncthreads();
    if (t < 64){
        double ss = 0.0, sq = 0.0;
#pragma unroll
        for (int i = 0; i < 16; ++i){ ss += (double)S_s[i][t]; sq += (double)S_q[i][t]; }
        int cp = blockIdx.x & (NCOPY-1);
        atomicAdd(&accumOut[cp*256 + t], ss);
        atomicAdd(&accumOut[cp*256 + 128 + t], sq);
    }
}

// ---------------------------------------------------------------- layer 2: BN+relu+GEMM K=64 -> 128 + fused stats + fused max/min POOLING
// Pooling in f32 pre-BN space; final kernel applies BN and picks max/min by
// sign(scale). z2 (67 MB x2 traffic) is never materialized.
__global__ __launch_bounds__(256) void layer2_mfma(const uint16_t* __restrict__ zin,
                                                   const double* __restrict__ accumIn,
                                                   const float* __restrict__ g,
                                                   const float* __restrict__ be,
                                                   const uint16_t* __restrict__ wb,
                                                   const float* __restrict__ bias,
                                                   float2* __restrict__ pool,
                                                   double* __restrict__ accumOut){
    constexpr int NT = 8;
    __shared__ float sc_l[64], sh_l[64];
    __shared__ float S_s[16][128], S_q[16][128];
    __shared__ float P_mx[16][128], P_mn[16][128];
    const int t = threadIdx.x;
    if (t < 64){
        double s = 0.0, qq = 0.0;
#pragma unroll
        for (int cp = 0; cp < NCOPY; ++cp){
            s  += accumIn[cp*256 + t];
            qq += accumIn[cp*256 + 128 + t];
        }
        double mean = s / (double)NROWS;
        double var  = qq / (double)NROWS - mean*mean;
        double rs = 1.0 / sqrt(var + 1e-5);
        double scv = (double)g[t] * rs;
        sc_l[t] = (float)scv;
        sh_l[t] = (float)((double)be[t] - mean*scv);
    }
    __syncthreads();

    const int wave = t >> 6, lane = t & 63;
    const int q = lane >> 4, l16 = lane & 15;
    const int r0 = blockIdx.x*64 + wave*16;

    bf16x8 Bf[NT][2];
#pragma unroll
    for (int nt = 0; nt < NT; ++nt)
#pragma unroll
        for (int s = 0; s < 2; ++s)
            Bf[nt][s] = load_bf8(wb + (nt*16 + l16)*64 + s*32 + q*8);

    float sc[2][8], sh[2][8];
#pragma unroll
    for (int s = 0; s < 2; ++s)
#pragma unroll
        for (int j = 0; j < 8; ++j){
            sc[s][j] = sc_l[s*32 + q*8 + j];
            sh[s][j] = sh_l[s*32 + q*8 + j];
        }

    f32x4 acc[NT];
#pragma unroll
    for (int nt = 0; nt < NT; ++nt) acc[nt] = (f32x4){0.f,0.f,0.f,0.f};

    const uint16_t* zr = zin + (size_t)(r0 + l16)*64;
#pragma unroll
    for (int s = 0; s < 2; ++s){
        uint4 u = *reinterpret_cast<const uint4*>(zr + s*32 + q*8);
        float h[8];
        h[0] = bf2f((uint16_t)(u.x & 0xFFFF)); h[1] = bf2f((uint16_t)(u.x >> 16));
        h[2] = bf2f((uint16_t)(u.y & 0xFFFF)); h[3] = bf2f((uint16_t)(u.y >> 16));
        h[4] = bf2f((uint16_t)(u.z & 0xFFFF)); h[5] = bf2f((uint16_t)(u.z >> 16));
        h[6] = bf2f((uint16_t)(u.w & 0xFFFF)); h[7] = bf2f((uint16_t)(u.w >> 16));
        bf16x8 a;
#pragma unroll
        for (int j = 0; j < 8; ++j){
            float v = fmaxf(fmaf(h[j], sc[s][j], sh[s][j]), 0.f);
            a[j] = (short)f2bf(v);
        }
#pragma unroll
        for (int nt = 0; nt < NT; ++nt)
            acc[nt] = __builtin_amdgcn_mfma_f32_16x16x32_bf16(a, Bf[nt][s], acc[nt], 0, 0, 0);
    }
#pragma unroll
    for (int nt = 0; nt < NT; ++nt){
        int c = nt*16 + l16;
        float bb = bias[c];
        float sps = 0.f, spq = 0.f;
        float mx = -1e30f, mn = 1e30f;
#pragma unroll
        for (int reg = 0; reg < 4; ++reg){
            float h = acc[nt][reg] + bb;
            sps += h;
            spq = fmaf(h, h, spq);
            mx = fmaxf(mx, h);
            mn = fminf(mn, h);
        }
        S_s[wave*4 + q][c] = sps;
        S_q[wave*4 + q][c] = spq;
        P_mx[wave*4 + q][c] = mx;
        P_mn[wave*4 + q][c] = mn;
    }
    __syncthreads();
    if (t < 128){
        double ss = 0.0, sq = 0.0;
#pragma unroll
        for (int i = 0; i < 16; ++i){ ss += (double)S_s[i][t]; sq += (double)S_q[i][t]; }
        int cp = blockIdx.x & (NCOPY-1);
        atomicAdd(&accumOut[cp*256 + t], ss);
        atomicAdd(&accumOut[cp*256 + 128 + t], sq);
    }
    // pooling: block covers 2 groups of 32 rows (= 2 (b,s) cells)
    {
        int gidx = t >> 7;          // 0..1
        int c = t & 127;
        float mx = -1e30f, mn = 1e30f;
#pragma unroll
        for (int i = 0; i < 8; ++i){
            mx = fmaxf(mx, P_mx[gidx*8 + i][c]);
            mn = fminf(mn, P_mn[gidx*8 + i][c]);
        }
        pool[(size_t)(blockIdx.x*2 + gidx)*128 + c] = make_float2(mx, mn);
    }
}

// ---------------------------------------------------------------- final: inline BN-param + select max/min by sign(scale) + BN + relu + transpose
__global__ __launch_bounds__(256) void final_kernel(const float2* __restrict__ pool,
                                                    const double* __restrict__ accumIn,
                                                    const float* __restrict__ g,
                                                    const float* __restrict__ be,
                                                    float* __restrict__ out){
    __shared__ float sc_l[128], sh_l[128];
    const int t0 = threadIdx.x;
    if (t0 < 128){
        double s = 0.0, qq = 0.0;
#pragma unroll
        for (int cp = 0; cp < NCOPY; ++cp){
            s  += accumIn[cp*256 + t0];
            qq += accumIn[cp*256 + 128 + t0];
        }
        double mean = s / (double)NROWS;
        double var  = qq / (double)NROWS - mean*mean;
        double rs = 1.0 / sqrt(var + 1e-5);
        double scv = (double)g[t0] * rs;
        sc_l[t0] = (float)scv;
        sh_l[t0] = (float)((double)be[t0] - mean*scv);
    }
    __syncthreads();

    int t = blockIdx.x*256 + threadIdx.x;   // 1048576 == pool linear index
    int o = t & 127;
    int s = (t >> 7) & 1023;
    int b = t >> 17;
    float2 p = pool[t];
    float sc = sc_l[o], sh = sh_l[o];
    float zsel = (sc >= 0.f) ? p.x : p.y;
    float y = fmaxf(fmaf(zsel, sc, sh), 0.f);
    out[24576 + ((size_t)b << 17) + ((size_t)o << 10) + s] = y;
}

// ---------------------------------------------------------------- launch
extern "C" void kernel_launch(void* const* d_in, const int* in_sizes, int n_in,
                              void* d_out, int out_size, void* d_ws, size_t ws_size,
                              hipStream_t stream) {
    const float* xyz = (const float*)d_in[0];
    const float* pts = (const float*)d_in[1];
    const float* w0  = (const float*)d_in[2];
    const float* b0  = (const float*)d_in[3];
    const float* g0  = (const float*)d_in[4];
    const float* be0 = (const float*)d_in[5];
    const float* w1  = (const float*)d_in[6];
    const float* b1  = (const float*)d_in[7];
    const float* g1  = (const float*)d_in[8];
    const float* be1 = (const float*)d_in[9];
    const float* w2  = (const float*)d_in[10];
    const float* b2  = (const float*)d_in[11];
    const float* g2  = (const float*)d_in[12];
    const float* be2 = (const float*)d_in[13];
    float* out = (float*)d_out;

    char* ws = (char*)d_ws;
    // accum: 3 layers x NCOPY x 256 doubles = 196608 B
    double*   accum0 = (double*)(ws + 0);
    double*   accum1 = (double*)(ws + 65536);
    double*   accum2 = (double*)(ws + 131072);
    uint16_t* w0b    = (uint16_t*)(ws + 196608);    // 12288 B
    uint16_t* w1b    = (uint16_t*)(ws + 208896);    // 8192 B
    uint16_t* w2b    = (uint16_t*)(ws + 217088);    // 16384 B
    uint16_t* z0     = (uint16_t*)(ws + 262144);    // 33554432 B
    uint16_t* z1     = (uint16_t*)(ws + 33816576);  // 33554432 B
    float2*   pool   = (float2*)  (ws + 67371008);  // 8388608 B
    int*      idx    = (int*)     (ws + 75759616);  // 1048576 B -> ends 76808192

    fps_prep_kernel<<<NB + 32, 256, 0, stream>>>(xyz, out, w0, w1, w2,
                                                 w0b, w1b, w2b, accum0);
    qball_kernel<<<2048, 256, 0, stream>>>(xyz, out, idx);
    layer0_mfma<<<4096, 256, 0, stream>>>(xyz, pts, idx, out, w0b, b0, z0, accum0);
    layer1_mfma<<<4096, 256, 0, stream>>>(z0, accum0, g0, be0, w1b, b1, z1, accum1);
    layer2_mfma<<<4096, 256, 0, stream>>>(z1, accum1, g1, be1, w2b, b2, pool, accum2);
    final_kernel<<<4096, 256, 0, stream>>>(pool, accum2, g2, be2, out);
}

// Round 13
// 838.572 us; speedup vs baseline: 1.1874x; 1.0085x over previous
//
#include <hip/hip_runtime.h>
#include <stdint.h>

#define NB 8
#define NPTS 4096
#define NS 1024
#define NK 32
#define NROWS (NB*NS*NK)   // 262144
#define R2 0.04f
#define NCOPY 32           // atomic spreading copies for stats accum
#define HLP 248            // helper blocks fused into fps dispatch

typedef __attribute__((ext_vector_type(8))) short bf16x8;   // 8 bf16 in 4 VGPRs
typedef __attribute__((ext_vector_type(4))) float f32x4;    // MFMA 16x16 accumulator
typedef __attribute__((ext_vector_type(2))) float f32x2;    // packed fp32 (v_pk_*)

__device__ __forceinline__ float bf2f(uint16_t u){
    uint32_t v = ((uint32_t)u) << 16;
    return __uint_as_float(v);
}
__device__ __forceinline__ uint16_t f2bf(float f){
    uint32_t u = __float_as_uint(f);
    uint32_t r = (u + 0x7FFFu + ((u >> 16) & 1u)) >> 16;
    return (uint16_t)r;
}
__device__ __forceinline__ bf16x8 load_bf8(const uint16_t* p){
    return *reinterpret_cast<const bf16x8*>(p);
}

// 64-bit max with a DPP-moved partner; masked-off / invalid lanes receive 0,
// which never wins (low word of a real key is ~idx >= 0xFFFFF000 != 0).
#define DPPMAX64(key, ctrl, rmask)                                             \
    {                                                                          \
        uint32_t _lo = (uint32_t)(key), _hi = (uint32_t)((key) >> 32);         \
        uint32_t _olo = (uint32_t)__builtin_amdgcn_update_dpp(                 \
            0, (int)_lo, (ctrl), (rmask), 0xf, true);                          \
        uint32_t _ohi = (uint32_t)__builtin_amdgcn_update_dpp(                 \
            0, (int)_hi, (ctrl), (rmask), 0xf, true);                          \
        unsigned long long _o = (((unsigned long long)_ohi) << 32) | _olo;     \
        key = (_o > (key)) ? _o : (key);                                       \
    }

// ---------------------------------------------------------------- FPS (+ fused prep/ptsconv on helper blocks)
// fps body is the r10 kernel VERBATIM (measured 582 us — best of 9 variants).
// Proven-regression list (do not retry): coord-carry cand (r5), float4 LDS
// coords (r8), 512 threads (r9), ballot owner-find / equality-mask argmax
// (r5, r11). Proven wins: DPP-VALU u64 reduce (r3), pk-f32 distance (r10).
// DO NOT TOUCH the distance math: contract(off), a+(-c) == a-c IEEE —
// selection is bit-exact vs reference (verified r2-r12).
// Blocks 8..255 (248 helpers on otherwise-idle CUs): weight fp32->bf16,
// accum zeroing, and pts -> padded 96-entry bf16 rows (for layer0's gather:
// 192 B/row aligned, f2bf pre-applied — bit-identical to in-kernel convert).
#define FT 16
__global__ __launch_bounds__(256) void fps_prep_kernel(const float* __restrict__ xyz,
                                                       float* __restrict__ out_newxyz,
                                                       const float* __restrict__ pts,
                                                       const float* __restrict__ w0,
                                                       const float* __restrict__ w1,
                                                       const float* __restrict__ w2,
                                                       uint16_t* __restrict__ w0b,
                                                       uint16_t* __restrict__ w1b,
                                                       uint16_t* __restrict__ w2b,
                                                       uint16_t* __restrict__ ptsb,
                                                       double* __restrict__ accumAll){
    __shared__ float LX[NPTS], LY[NPTS], LZ[NPTS];
    __shared__ float4 SC[NS];
    __shared__ alignas(16) unsigned long long cand[2][4];
    if (blockIdx.x >= NB){
        // ---- helper path (blocks 8..255) ----
        int t = (blockIdx.x - NB)*256 + threadIdx.x;   // 0..63487
        int stride = HLP*256;
        for (int i = t; i < 3*NCOPY*256; i += stride) accumAll[i] = 0.0;
        for (int i = t; i < 64*96; i += stride){
            int n = i/96, c = i%96;
            w0b[i] = (c < 67) ? f2bf(w0[n*67 + c]) : (uint16_t)0;
        }
        for (int i = t; i < 64*64; i += stride)  w1b[i] = f2bf(w1[i]);
        for (int i = t; i < 128*64; i += stride) w2b[i] = f2bf(w2[i]);
        // pts -> padded bf16 rows: ptsb[row*96 + k] = (3<=k<67)? bf16(pts[row*64+k-3]) : 0
        int wv = t >> 6, lane = t & 63;                // 992 waves
        for (int row = wv; row < NB*NPTS; row += HLP*4){
            const float* src = pts + (size_t)row*64;
            uint16_t* dst = ptsb + (size_t)row*96;
            dst[lane] = (lane >= 3) ? f2bf(src[lane-3]) : (uint16_t)0;
            if (lane < 32){
                int k = 64 + lane;
                dst[k] = (k < 67) ? f2bf(src[k-3]) : (uint16_t)0;
            }
        }
        return;
    }
    // ---- fps path (blocks 0..7), r10 verbatim ----
    const int b = blockIdx.x, t = threadIdx.x;
    const float* base = xyz + (size_t)b * (NPTS*3);
    f32x2 px2[FT/2], py2[FT/2], pz2[FT/2], pd2[FT/2];
#pragma unroll
    for (int j = 0; j < FT/2; ++j){
        int i = t*FT + 2*j;
        float x0 = base[i*3+0], y0 = base[i*3+1], z0 = base[i*3+2];
        float x1 = base[i*3+3], y1 = base[i*3+4], z1 = base[i*3+5];
        px2[j] = (f32x2){x0, x1};
        py2[j] = (f32x2){y0, y1};
        pz2[j] = (f32x2){z0, z1};
        pd2[j] = (f32x2){1e10f, 1e10f};
        LX[i]=x0; LY[i]=y0; LZ[i]=z0;
        LX[i+1]=x1; LY[i+1]=y1; LZ[i+1]=z1;
    }
    __syncthreads();
    int cur = 0;
    const int wave = t >> 6, lane = t & 63;
    for (int s = 0; s < NS; ++s){
        float cx = LX[cur], cy = LY[cur], cz = LZ[cur];
        if (t == 0) SC[s] = make_float4(cx, cy, cz, 0.f);
        f32x2 ncx = (f32x2){-cx, -cx};
        f32x2 ncy = (f32x2){-cy, -cy};
        f32x2 ncz = (f32x2){-cz, -cz};
        float bestd = -1.0f; int besti = 0;
#pragma unroll
        for (int j = 0; j < FT/2; ++j){
            f32x2 d2;
            {
#pragma clang fp contract(off)
                f32x2 dx = px2[j] + ncx;       // pk_add; == px - cx bit-exact
                f32x2 dy = py2[j] + ncy;
                f32x2 dz = pz2[j] + ncz;
                f32x2 xx = dx*dx, yy = dy*dy, zz = dz*dz;   // pk_mul
                d2 = (xx + yy) + zz;                        // pk_add x2
            }
            f32x2 nd;
            nd.x = fminf(pd2[j].x, d2.x);
            nd.y = fminf(pd2[j].y, d2.y);
            pd2[j] = nd;
            if (nd.x > bestd){ bestd = nd.x; besti = t*FT + 2*j; }
            if (nd.y > bestd){ bestd = nd.y; besti = t*FT + 2*j + 1; }
        }
        unsigned long long key =
            (((unsigned long long)__float_as_uint(bestd)) << 32) |
            (unsigned long long)(~(unsigned)besti);
        DPPMAX64(key, 0x111, 0xf);   // row_shr:1
        DPPMAX64(key, 0x112, 0xf);   // row_shr:2
        DPPMAX64(key, 0x114, 0xf);   // row_shr:4
        DPPMAX64(key, 0x118, 0xf);   // row_shr:8
        DPPMAX64(key, 0x142, 0xa);   // row_bcast:15 -> rows 1,3
        DPPMAX64(key, 0x143, 0xc);   // row_bcast:31 -> rows 2,3
        int p = s & 1;
        if (lane == 63) cand[p][wave] = key;
        __syncthreads();
        ulonglong2 c01 = *reinterpret_cast<const ulonglong2*>(&cand[p][0]);
        ulonglong2 c23 = *reinterpret_cast<const ulonglong2*>(&cand[p][2]);
        unsigned long long m01 = (c01.x > c01.y) ? c01.x : c01.y;
        unsigned long long m23 = (c23.x > c23.y) ? c23.x : c23.y;
        unsigned long long km  = (m01 > m23) ? m01 : m23;
        cur = (int)(~(uint32_t)km);
    }
    __syncthreads();
    for (int i = t; i < NS; i += 256){
        float4 c = SC[i];
        float* o = out_newxyz + ((size_t)b*NS + i)*3;
        o[0] = c.x; o[1] = c.y; o[2] = c.z;
    }
}

// ---------------------------------------------------------------- query ball
// UNCHANGED (verified).
__global__ __launch_bounds__(256) void qball_kernel(const float* __restrict__ xyz,
                                                    const float* __restrict__ newxyz,
                                                    int* __restrict__ idx_out){
    int gid = blockIdx.x*256 + threadIdx.x;
    int w = gid >> 6, lane = gid & 63;
    int b = w >> 10;
    const float* q = newxyz + (size_t)w*3;
    float qx = q[0], qy = q[1], qz = q[2];
    float qn = qx*qx;
    qn = fmaf(qy, qy, qn);
    qn = fmaf(qz, qz, qn);
    const float* base = xyz + (size_t)b * (NPTS*3);
    int cnt = 0, first = 0;
    for (int c0 = 0; c0 < NPTS; c0 += 64){
        int i = c0 + lane;
        float x = base[i*3+0], y = base[i*3+1], z = base[i*3+2];
        float xn = x*x;
        xn = fmaf(y, y, xn);
        xn = fmaf(z, z, xn);
        float dot = qx*x;
        dot = fmaf(qy, y, dot);
        dot = fmaf(qz, z, dot);
        float d;
        {
#pragma clang fp contract(off)
            d = -2.0f * dot;
            d = d + qn;
            d = d + xn;
        }
        bool in = !(d > R2);
        unsigned long long m = __ballot(in);
        if (in){
            int rank = __popcll(m & ((1ull << lane) - 1ull));
            int pos = cnt + rank;
            if (pos < NK) idx_out[(size_t)w*NK + pos] = i;
        }
        if (cnt == 0 && m) first = c0 + (__ffsll((unsigned long long)m) - 1);
        cnt += __popcll(m);
        if (cnt >= NK) break;
    }
    if (cnt < NK){
        for (int p = cnt + lane; p < NK; p += 64) idx_out[(size_t)w*NK + p] = first;
    }
}

// ---------------------------------------------------------------- layer 0: gather + GEMM 262144 x 96 -> 64 (MFMA) + fused stats
// A-operand now loads pre-converted padded bf16 pts rows (192 B aligned);
// only the 3 xyz-diff slots (s==0, q==0, j<3) are fixed up in-register.
__global__ __launch_bounds__(256) void layer0_mfma(const float* __restrict__ xyz,
                                                   const uint16_t* __restrict__ ptsb,
                                                   const int* __restrict__ idx,
                                                   const float* __restrict__ newxyz,
                                                   const uint16_t* __restrict__ w0b,
                                                   const float* __restrict__ b0,
                                                   uint16_t* __restrict__ z0,
                                                   double* __restrict__ accumOut){
    __shared__ float S_s[16][64], S_q[16][64];
    const int wave = threadIdx.x >> 6, lane = threadIdx.x & 63;
    const int q = lane >> 4, l16 = lane & 15;
    const int r0 = blockIdx.x*64 + wave*16;
    const int row = r0 + l16;
    const int b = row >> 15;
    const int bs = row >> 5;
    const int id = idx[row];
    const uint16_t* prow = ptsb + (size_t)((b << 12) + id)*96;
    const float* xr   = xyz + (((size_t)b << 12) + id)*3;
    const float* qr   = newxyz + (size_t)bs*3;
    float d0 = xr[0]-qr[0], d1 = xr[1]-qr[1], d2 = xr[2]-qr[2];

    bf16x8 Bf[4][3];
#pragma unroll
    for (int nt = 0; nt < 4; ++nt)
#pragma unroll
        for (int s = 0; s < 3; ++s)
            Bf[nt][s] = load_bf8(w0b + (nt*16 + l16)*96 + s*32 + q*8);

    f32x4 acc[4];
#pragma unroll
    for (int nt = 0; nt < 4; ++nt) acc[nt] = (f32x4){0.f,0.f,0.f,0.f};

#pragma unroll
    for (int s = 0; s < 3; ++s){
        bf16x8 a = load_bf8(prow + s*32 + q*8);
        if (s == 0 && q == 0){
            a[0] = (short)f2bf(d0);
            a[1] = (short)f2bf(d1);
            a[2] = (short)f2bf(d2);
        }
#pragma unroll
        for (int nt = 0; nt < 4; ++nt)
            acc[nt] = __builtin_amdgcn_mfma_f32_16x16x32_bf16(a, Bf[nt][s], acc[nt], 0, 0, 0);
    }
    // C/D: col=lane&15, row=quad*4+reg. Epilogue: bias, store, f32 stats partials.
#pragma unroll
    for (int nt = 0; nt < 4; ++nt){
        int c = nt*16 + l16;
        float bb = b0[c];
        float sps = 0.f, spq = 0.f;
#pragma unroll
        for (int reg = 0; reg < 4; ++reg){
            int rr = r0 + q*4 + reg;
            float h = acc[nt][reg] + bb;
            sps += h;
            spq = fmaf(h, h, spq);
            z0[(size_t)rr*64 + c] = f2bf(h);
        }
        S_s[wave*4 + q][c] = sps;
        S_q[wave*4 + q][c] = spq;
    }
    __syncthreads();
    int t = threadIdx.x;
    if (t < 64){
        double ss = 0.0, sq = 0.0;
#pragma unroll
        for (int i = 0; i < 16; ++i){ ss += (double)S_s[i][t]; sq += (double)S_q[i][t]; }
        int cp = blockIdx.x & (NCOPY-1);
        atomicAdd(&accumOut[cp*256 + t], ss);
        atomicAdd(&accumOut[cp*256 + 128 + t], sq);
    }
}

// ---------------------------------------------------------------- layer 1: inline BN-param + BN+relu+GEMM K=64 + fused stats
__global__ __launch_bounds__(256) void layer1_mfma(const uint16_t* __restrict__ zin,
                                                   const double* __restrict__ accumIn,
                                                   const float* __restrict__ g,
                                                   const float* __restrict__ be,
                                                   const uint16_t* __restrict__ wb,
                                                   const float* __restrict__ bias,
                                                   uint16_t* __restrict__ zout,
                                                   double* __restrict__ accumOut){
    constexpr int NT = 4;
    __shared__ float sc_l[64], sh_l[64];
    __shared__ float S_s[16][64], S_q[16][64];
    const int t = threadIdx.x;
    if (t < 64){
        double s = 0.0, qq = 0.0;
#pragma unroll
        for (int cp = 0; cp < NCOPY; ++cp){
            s  += accumIn[cp*256 + t];
            qq += accumIn[cp*256 + 128 + t];
        }
        double mean = s / (double)NROWS;
        double var  = qq / (double)NROWS - mean*mean;
        double rs = 1.0 / sqrt(var + 1e-5);
        double scv = (double)g[t] * rs;
        sc_l[t] = (float)scv;
        sh_l[t] = (float)((double)be[t] - mean*scv);
    }
    __syncthreads();

    const int wave = t >> 6, lane = t & 63;
    const int q = lane >> 4, l16 = lane & 15;
    const int r0 = blockIdx.x*64 + wave*16;

    bf16x8 Bf[NT][2];
#pragma unroll
    for (int nt = 0; nt < NT; ++nt)
#pragma unroll
        for (int s = 0; s < 2; ++s)
            Bf[nt][s] = load_bf8(wb + (nt*16 + l16)*64 + s*32 + q*8);

    float sc[2][8], sh[2][8];
#pragma unroll
    for (int s = 0; s < 2; ++s)
#pragma unroll
        for (int j = 0; j < 8; ++j){
            sc[s][j] = sc_l[s*32 + q*8 + j];
            sh[s][j] = sh_l[s*32 + q*8 + j];
        }

    f32x4 acc[NT];
#pragma unroll
    for (int nt = 0; nt < NT; ++nt) acc[nt] = (f32x4){0.f,0.f,0.f,0.f};

    const uint16_t* zr = zin + (size_t)(r0 + l16)*64;
#pragma unroll
    for (int s = 0; s < 2; ++s){
        uint4 u = *reinterpret_cast<const uint4*>(zr + s*32 + q*8);
        float h[8];
        h[0] = bf2f((uint16_t)(u.x & 0xFFFF)); h[1] = bf2f((uint16_t)(u.x >> 16));
        h[2] = bf2f((uint16_t)(u.y & 0xFFFF)); h[3] = bf2f((uint16_t)(u.y >> 16));
        h[4] = bf2f((uint16_t)(u.z & 0xFFFF)); h[5] = bf2f((uint16_t)(u.z >> 16));
        h[6] = bf2f((uint16_t)(u.w & 0xFFFF)); h[7] = bf2f((uint16_t)(u.w >> 16));
        bf16x8 a;
#pragma unroll
        for (int j = 0; j < 8; ++j){
            float v = fmaxf(fmaf(h[j], sc[s][j], sh[s][j]), 0.f);
            a[j] = (short)f2bf(v);
        }
#pragma unroll
        for (int nt = 0; nt < NT; ++nt)
            acc[nt] = __builtin_amdgcn_mfma_f32_16x16x32_bf16(a, Bf[nt][s], acc[nt], 0, 0, 0);
    }
#pragma unroll
    for (int nt = 0; nt < NT; ++nt){
        int c = nt*16 + l16;
        float bb = bias[c];
        float sps = 0.f, spq = 0.f;
#pragma unroll
        for (int reg = 0; reg < 4; ++reg){
            int rr = r0 + q*4 + reg;
            float h = acc[nt][reg] + bb;
            sps += h;
            spq = fmaf(h, h, spq);
            zout[(size_t)rr*64 + c] = f2bf(h);
        }
        S_s[wave*4 + q][c] = sps;
        S_q[wave*4 + q][c] = spq;
    }
    __syncthreads();
    if (t < 64){
        double ss = 0.0, sq = 0.0;
#pragma unroll
        for (int i = 0; i < 16; ++i){ ss += (double)S_s[i][t]; sq += (double)S_q[i][t]; }
        int cp = blockIdx.x & (NCOPY-1);
        atomicAdd(&accumOut[cp*256 + t], ss);
        atomicAdd(&accumOut[cp*256 + 128 + t], sq);
    }
}

// ---------------------------------------------------------------- layer 2: BN+relu+GEMM K=64 -> 128 + fused stats + fused max/min POOLING
// Pooling in f32 pre-BN space; final kernel applies BN and picks max/min by
// sign(scale). z2 (67 MB x2 traffic) is never materialized.
__global__ __launch_bounds__(256) void layer2_mfma(const uint16_t* __restrict__ zin,
                                                   const double* __restrict__ accumIn,
                                                   const float* __restrict__ g,
                                                   const float* __restrict__ be,
                                                   const uint16_t* __restrict__ wb,
                                                   const float* __restrict__ bias,
                                                   float2* __restrict__ pool,
                                                   double* __restrict__ accumOut){
    constexpr int NT = 8;
    __shared__ float sc_l[64], sh_l[64];
    __shared__ float S_s[16][128], S_q[16][128];
    __shared__ float P_mx[16][128], P_mn[16][128];
    const int t = threadIdx.x;
    if (t < 64){
        double s = 0.0, qq = 0.0;
#pragma unroll
        for (int cp = 0; cp < NCOPY; ++cp){
            s  += accumIn[cp*256 + t];
            qq += accumIn[cp*256 + 128 + t];
        }
        double mean = s / (double)NROWS;
        double var  = qq / (double)NROWS - mean*mean;
        double rs = 1.0 / sqrt(var + 1e-5);
        double scv = (double)g[t] * rs;
        sc_l[t] = (float)scv;
        sh_l[t] = (float)((double)be[t] - mean*scv);
    }
    __syncthreads();

    const int wave = t >> 6, lane = t & 63;
    const int q = lane >> 4, l16 = lane & 15;
    const int r0 = blockIdx.x*64 + wave*16;

    bf16x8 Bf[NT][2];
#pragma unroll
    for (int nt = 0; nt < NT; ++nt)
#pragma unroll
        for (int s = 0; s < 2; ++s)
            Bf[nt][s] = load_bf8(wb + (nt*16 + l16)*64 + s*32 + q*8);

    float sc[2][8], sh[2][8];
#pragma unroll
    for (int s = 0; s < 2; ++s)
#pragma unroll
        for (int j = 0; j < 8; ++j){
            sc[s][j] = sc_l[s*32 + q*8 + j];
            sh[s][j] = sh_l[s*32 + q*8 + j];
        }

    f32x4 acc[NT];
#pragma unroll
    for (int nt = 0; nt < NT; ++nt) acc[nt] = (f32x4){0.f,0.f,0.f,0.f};

    const uint16_t* zr = zin + (size_t)(r0 + l16)*64;
#pragma unroll
    for (int s = 0; s < 2; ++s){
        uint4 u = *reinterpret_cast<const uint4*>(zr + s*32 + q*8);
        float h[8];
        h[0] = bf2f((uint16_t)(u.x & 0xFFFF)); h[1] = bf2f((uint16_t)(u.x >> 16));
        h[2] = bf2f((uint16_t)(u.y & 0xFFFF)); h[3] = bf2f((uint16_t)(u.y >> 16));
        h[4] = bf2f((uint16_t)(u.z & 0xFFFF)); h[5] = bf2f((uint16_t)(u.z >> 16));
        h[6] = bf2f((uint16_t)(u.w & 0xFFFF)); h[7] = bf2f((uint16_t)(u.w >> 16));
        bf16x8 a;
#pragma unroll
        for (int j = 0; j < 8; ++j){
            float v = fmaxf(fmaf(h[j], sc[s][j], sh[s][j]), 0.f);
            a[j] = (short)f2bf(v);
        }
#pragma unroll
        for (int nt = 0; nt < NT; ++nt)
            acc[nt] = __builtin_amdgcn_mfma_f32_16x16x32_bf16(a, Bf[nt][s], acc[nt], 0, 0, 0);
    }
#pragma unroll
    for (int nt = 0; nt < NT; ++nt){
        int c = nt*16 + l16;
        float bb = bias[c];
        float sps = 0.f, spq = 0.f;
        float mx = -1e30f, mn = 1e30f;
#pragma unroll
        for (int reg = 0; reg < 4; ++reg){
            float h = acc[nt][reg] + bb;
            sps += h;
            spq = fmaf(h, h, spq);
            mx = fmaxf(mx, h);
            mn = fminf(mn, h);
        }
        S_s[wave*4 + q][c] = sps;
        S_q[wave*4 + q][c] = spq;
        P_mx[wave*4 + q][c] = mx;
        P_mn[wave*4 + q][c] = mn;
    }
    __syncthreads();
    if (t < 128){
        double ss = 0.0, sq = 0.0;
#pragma unroll
        for (int i = 0; i < 16; ++i){ ss += (double)S_s[i][t]; sq += (double)S_q[i][t]; }
        int cp = blockIdx.x & (NCOPY-1);
        atomicAdd(&accumOut[cp*256 + t], ss);
        atomicAdd(&accumOut[cp*256 + 128 + t], sq);
    }
    // pooling: block covers 2 groups of 32 rows (= 2 (b,s) cells)
    {
        int gidx = t >> 7;          // 0..1
        int c = t & 127;
        float mx = -1e30f, mn = 1e30f;
#pragma unroll
        for (int i = 0; i < 8; ++i){
            mx = fmaxf(mx, P_mx[gidx*8 + i][c]);
            mn = fminf(mn, P_mn[gidx*8 + i][c]);
        }
        pool[(size_t)(blockIdx.x*2 + gidx)*128 + c] = make_float2(mx, mn);
    }
}

// ---------------------------------------------------------------- final: inline BN-param + select max/min by sign(scale) + BN + relu + transpose
__global__ __launch_bounds__(256) void final_kernel(const float2* __restrict__ pool,
                                                    const double* __restrict__ accumIn,
                                                    const float* __restrict__ g,
                                                    const float* __restrict__ be,
                                                    float* __restrict__ out){
    __shared__ float sc_l[128], sh_l[128];
    const int t0 = threadIdx.x;
    if (t0 < 128){
        double s = 0.0, qq = 0.0;
#pragma unroll
        for (int cp = 0; cp < NCOPY; ++cp){
            s  += accumIn[cp*256 + t0];
            qq += accumIn[cp*256 + 128 + t0];
        }
        double mean = s / (double)NROWS;
        double var  = qq / (double)NROWS - mean*mean;
        double rs = 1.0 / sqrt(var + 1e-5);
        double scv = (double)g[t0] * rs;
        sc_l[t0] = (float)scv;
        sh_l[t0] = (float)((double)be[t0] - mean*scv);
    }
    __syncthreads();

    int t = blockIdx.x*256 + threadIdx.x;   // 1048576 == pool linear index
    int o = t & 127;
    int s = (t >> 7) & 1023;
    int b = t >> 17;
    float2 p = pool[t];
    float sc = sc_l[o], sh = sh_l[o];
    float zsel = (sc >= 0.f) ? p.x : p.y;
    float y = fmaxf(fmaf(zsel, sc, sh), 0.f);
    out[24576 + ((size_t)b << 17) + ((size_t)o << 10) + s] = y;
}

// ---------------------------------------------------------------- launch
extern "C" void kernel_launch(void* const* d_in, const int* in_sizes, int n_in,
                              void* d_out, int out_size, void* d_ws, size_t ws_size,
                              hipStream_t stream) {
    const float* xyz = (const float*)d_in[0];
    const float* pts = (const float*)d_in[1];
    const float* w0  = (const float*)d_in[2];
    const float* b0  = (const float*)d_in[3];
    const float* g0  = (const float*)d_in[4];
    const float* be0 = (const float*)d_in[5];
    const float* w1  = (const float*)d_in[6];
    const float* b1  = (const float*)d_in[7];
    const float* g1  = (const float*)d_in[8];
    const float* be1 = (const float*)d_in[9];
    const float* w2  = (const float*)d_in[10];
    const float* b2  = (const float*)d_in[11];
    const float* g2  = (const float*)d_in[12];
    const float* be2 = (const float*)d_in[13];
    float* out = (float*)d_out;

    char* ws = (char*)d_ws;
    // accum: 3 layers x NCOPY x 256 doubles = 196608 B
    double*   accum0 = (double*)(ws + 0);
    double*   accum1 = (double*)(ws + 65536);
    double*   accum2 = (double*)(ws + 131072);
    uint16_t* w0b    = (uint16_t*)(ws + 196608);    // 12288 B
    uint16_t* w1b    = (uint16_t*)(ws + 208896);    // 8192 B
    uint16_t* w2b    = (uint16_t*)(ws + 217088);    // 16384 B
    uint16_t* ptsb   = (uint16_t*)(ws + 233472);    // 32768*96*2 = 6291456 B
    uint16_t* z0     = (uint16_t*)(ws + 6524928);   // 33554432 B
    uint16_t* z1     = (uint16_t*)(ws + 40079360);  // 33554432 B
    float2*   pool   = (float2*)  (ws + 73633792);  // 8388608 B
    int*      idx    = (int*)     (ws + 82022400);  // 1048576 B -> ends 83070976

    fps_prep_kernel<<<NB + HLP, 256, 0, stream>>>(xyz, out, pts, w0, w1, w2,
                                                  w0b, w1b, w2b, ptsb, accum0);
    qball_kernel<<<2048, 256, 0, stream>>>(xyz, out, idx);
    layer0_mfma<<<4096, 256, 0, stream>>>(xyz, ptsb, idx, out, w0b, b0, z0, accum0);
    layer1_mfma<<<4096, 256, 0, stream>>>(z0, accum0, g0, be0, w1b, b1, z1, accum1);
    layer2_mfma<<<4096, 256, 0, stream>>>(z1, accum1, g1, be1, w2b, b2, pool, accum2);
    final_kernel<<<4096, 256, 0, stream>>>(pool, accum2, g2, be2, out);
}

// Round 14
// 827.359 us; speedup vs baseline: 1.2035x; 1.0136x over previous
//
#include <hip/hip_runtime.h>
#include <stdint.h>

#define NB 8
#define NPTS 4096
#define NS 1024
#define NK 32
#define NROWS (NB*NS*NK)   // 262144
#define R2 0.04f
#define NCOPY 32           // atomic spreading copies for stats accum

typedef __attribute__((ext_vector_type(8))) short bf16x8;   // 8 bf16 in 4 VGPRs
typedef __attribute__((ext_vector_type(4))) float f32x4;    // MFMA 16x16 accumulator
typedef __attribute__((ext_vector_type(2))) float f32x2;    // packed fp32 (v_pk_*)

__device__ __forceinline__ float bf2f(uint16_t u){
    uint32_t v = ((uint32_t)u) << 16;
    return __uint_as_float(v);
}
__device__ __forceinline__ uint16_t f2bf(float f){
    uint32_t u = __float_as_uint(f);
    uint32_t r = (u + 0x7FFFu + ((u >> 16) & 1u)) >> 16;
    return (uint16_t)r;
}
__device__ __forceinline__ bf16x8 load_bf8(const uint16_t* p){
    return *reinterpret_cast<const bf16x8*>(p);
}

// 64-bit max with a DPP-moved partner; masked-off / invalid lanes receive 0,
// which never wins (low word of a real key is ~idx >= 0xFFFFF000 != 0).
#define DPPMAX64(key, ctrl, rmask)                                             \
    {                                                                          \
        uint32_t _lo = (uint32_t)(key), _hi = (uint32_t)((key) >> 32);         \
        uint32_t _olo = (uint32_t)__builtin_amdgcn_update_dpp(                 \
            0, (int)_lo, (ctrl), (rmask), 0xf, true);                          \
        uint32_t _ohi = (uint32_t)__builtin_amdgcn_update_dpp(                 \
            0, (int)_hi, (ctrl), (rmask), 0xf, true);                          \
        unsigned long long _o = (((unsigned long long)_ohi) << 32) | _olo;     \
        key = (_o > (key)) ? _o : (key);                                       \
    }

// ---------------------------------------------------------------- FPS
// r10 kernel VERBATIM — best of 11 measured variants (582 us standalone;
// total 828.5 us config). Serial floor: 1024 dependent argmax iters,
// ~1360 cyc each (~200 issue + ~1150 reduce/barrier/LDS tail).
// Proven-regression list (do not retry): coord-carry cand (r5), float4 LDS
// coords (r8), 512 threads (r9), ballot owner-find / equality-mask argmax
// (r5, r11), helper-block fusion of prep/ptsconv (r12: +17us, r13: net worse).
// Proven wins: DPP-VALU u64 reduce (r3), pk-f32 distance (r10).
// DO NOT TOUCH the distance math: contract(off), a+(-c) == a-c IEEE —
// selection is bit-exact vs reference (verified r2-r13).
#define FT 16
__global__ __launch_bounds__(256) void fps_kernel(const float* __restrict__ xyz,
                                                  float* __restrict__ out_newxyz){
    __shared__ float LX[NPTS], LY[NPTS], LZ[NPTS];
    __shared__ float4 SC[NS];
    __shared__ alignas(16) unsigned long long cand[2][4];
    const int b = blockIdx.x, t = threadIdx.x;
    const float* base = xyz + (size_t)b * (NPTS*3);
    f32x2 px2[FT/2], py2[FT/2], pz2[FT/2], pd2[FT/2];
#pragma unroll
    for (int j = 0; j < FT/2; ++j){
        int i = t*FT + 2*j;
        float x0 = base[i*3+0], y0 = base[i*3+1], z0 = base[i*3+2];
        float x1 = base[i*3+3], y1 = base[i*3+4], z1 = base[i*3+5];
        px2[j] = (f32x2){x0, x1};
        py2[j] = (f32x2){y0, y1};
        pz2[j] = (f32x2){z0, z1};
        pd2[j] = (f32x2){1e10f, 1e10f};
        LX[i]=x0; LY[i]=y0; LZ[i]=z0;
        LX[i+1]=x1; LY[i+1]=y1; LZ[i+1]=z1;
    }
    __syncthreads();
    int cur = 0;
    const int wave = t >> 6, lane = t & 63;
    for (int s = 0; s < NS; ++s){
        float cx = LX[cur], cy = LY[cur], cz = LZ[cur];
        if (t == 0) SC[s] = make_float4(cx, cy, cz, 0.f);
        f32x2 ncx = (f32x2){-cx, -cx};
        f32x2 ncy = (f32x2){-cy, -cy};
        f32x2 ncz = (f32x2){-cz, -cz};
        float bestd = -1.0f; int besti = 0;
#pragma unroll
        for (int j = 0; j < FT/2; ++j){
            f32x2 d2;
            {
#pragma clang fp contract(off)
                f32x2 dx = px2[j] + ncx;       // pk_add; == px - cx bit-exact
                f32x2 dy = py2[j] + ncy;
                f32x2 dz = pz2[j] + ncz;
                f32x2 xx = dx*dx, yy = dy*dy, zz = dz*dz;   // pk_mul
                d2 = (xx + yy) + zz;                        // pk_add x2
            }
            f32x2 nd;
            nd.x = fminf(pd2[j].x, d2.x);
            nd.y = fminf(pd2[j].y, d2.y);
            pd2[j] = nd;
            if (nd.x > bestd){ bestd = nd.x; besti = t*FT + 2*j; }
            if (nd.y > bestd){ bestd = nd.y; besti = t*FT + 2*j + 1; }
        }
        unsigned long long key =
            (((unsigned long long)__float_as_uint(bestd)) << 32) |
            (unsigned long long)(~(unsigned)besti);
        DPPMAX64(key, 0x111, 0xf);   // row_shr:1
        DPPMAX64(key, 0x112, 0xf);   // row_shr:2
        DPPMAX64(key, 0x114, 0xf);   // row_shr:4
        DPPMAX64(key, 0x118, 0xf);   // row_shr:8
        DPPMAX64(key, 0x142, 0xa);   // row_bcast:15 -> rows 1,3
        DPPMAX64(key, 0x143, 0xc);   // row_bcast:31 -> rows 2,3
        int p = s & 1;
        if (lane == 63) cand[p][wave] = key;
        __syncthreads();
        ulonglong2 c01 = *reinterpret_cast<const ulonglong2*>(&cand[p][0]);
        ulonglong2 c23 = *reinterpret_cast<const ulonglong2*>(&cand[p][2]);
        unsigned long long m01 = (c01.x > c01.y) ? c01.x : c01.y;
        unsigned long long m23 = (c23.x > c23.y) ? c23.x : c23.y;
        unsigned long long km  = (m01 > m23) ? m01 : m23;
        cur = (int)(~(uint32_t)km);
    }
    __syncthreads();
    for (int i = t; i < NS; i += 256){
        float4 c = SC[i];
        float* o = out_newxyz + ((size_t)b*NS + i)*3;
        o[0] = c.x; o[1] = c.y; o[2] = c.z;
    }
}

// ---------------------------------------------------------------- query ball
// UNCHANGED (verified).
__global__ __launch_bounds__(256) void qball_kernel(const float* __restrict__ xyz,
                                                    const float* __restrict__ newxyz,
                                                    int* __restrict__ idx_out){
    int gid = blockIdx.x*256 + threadIdx.x;
    int w = gid >> 6, lane = gid & 63;
    int b = w >> 10;
    const float* q = newxyz + (size_t)w*3;
    float qx = q[0], qy = q[1], qz = q[2];
    float qn = qx*qx;
    qn = fmaf(qy, qy, qn);
    qn = fmaf(qz, qz, qn);
    const float* base = xyz + (size_t)b * (NPTS*3);
    int cnt = 0, first = 0;
    for (int c0 = 0; c0 < NPTS; c0 += 64){
        int i = c0 + lane;
        float x = base[i*3+0], y = base[i*3+1], z = base[i*3+2];
        float xn = x*x;
        xn = fmaf(y, y, xn);
        xn = fmaf(z, z, xn);
        float dot = qx*x;
        dot = fmaf(qy, y, dot);
        dot = fmaf(qz, z, dot);
        float d;
        {
#pragma clang fp contract(off)
            d = -2.0f * dot;
            d = d + qn;
            d = d + xn;
        }
        bool in = !(d > R2);
        unsigned long long m = __ballot(in);
        if (in){
            int rank = __popcll(m & ((1ull << lane) - 1ull));
            int pos = cnt + rank;
            if (pos < NK) idx_out[(size_t)w*NK + pos] = i;
        }
        if (cnt == 0 && m) first = c0 + (__ffsll((unsigned long long)m) - 1);
        cnt += __popcll(m);
        if (cnt >= NK) break;
    }
    if (cnt < NK){
        for (int p = cnt + lane; p < NK; p += 64) idx_out[(size_t)w*NK + p] = first;
    }
}

// ---------------------------------------------------------------- weight prep (fp32 -> bf16) + accum zeroing
__global__ void prep_kernel(const float* __restrict__ w0, const float* __restrict__ w1,
                            const float* __restrict__ w2, uint16_t* __restrict__ w0b,
                            uint16_t* __restrict__ w1b, uint16_t* __restrict__ w2b,
                            double* __restrict__ accumAll){
    int t = blockIdx.x*256 + threadIdx.x;
    int stride = gridDim.x*256;
    for (int i = t; i < 3*NCOPY*256; i += stride) accumAll[i] = 0.0;
    for (int i = t; i < 64*96; i += stride){
        int n = i/96, c = i%96;
        w0b[i] = (c < 67) ? f2bf(w0[n*67 + c]) : (uint16_t)0;
    }
    for (int i = t; i < 64*64; i += stride)  w1b[i] = f2bf(w1[i]);
    for (int i = t; i < 128*64; i += stride) w2b[i] = f2bf(w2[i]);
}

// ---------------------------------------------------------------- layer 0: gather + GEMM 262144 x 96 -> 64 (MFMA) + fused stats
__global__ __launch_bounds__(256) void layer0_mfma(const float* __restrict__ xyz,
                                                   const float* __restrict__ pts,
                                                   const int* __restrict__ idx,
                                                   const float* __restrict__ newxyz,
                                                   const uint16_t* __restrict__ w0b,
                                                   const float* __restrict__ b0,
                                                   uint16_t* __restrict__ z0,
                                                   double* __restrict__ accumOut){
    __shared__ float S_s[16][64], S_q[16][64];
    const int wave = threadIdx.x >> 6, lane = threadIdx.x & 63;
    const int q = lane >> 4, l16 = lane & 15;
    const int r0 = blockIdx.x*64 + wave*16;
    const int row = r0 + l16;
    const int b = row >> 15;
    const int bs = row >> 5;
    const int id = idx[row];
    const float* prow = pts + (((size_t)b << 12) + id)*64;
    const float* xr   = xyz + (((size_t)b << 12) + id)*3;
    const float* qr   = newxyz + (size_t)bs*3;
    float d0 = xr[0]-qr[0], d1 = xr[1]-qr[1], d2 = xr[2]-qr[2];

    bf16x8 Bf[4][3];
#pragma unroll
    for (int nt = 0; nt < 4; ++nt)
#pragma unroll
        for (int s = 0; s < 3; ++s)
            Bf[nt][s] = load_bf8(w0b + (nt*16 + l16)*96 + s*32 + q*8);

    f32x4 acc[4];
#pragma unroll
    for (int nt = 0; nt < 4; ++nt) acc[nt] = (f32x4){0.f,0.f,0.f,0.f};

#pragma unroll
    for (int s = 0; s < 3; ++s){
        const int k0 = s*32 + q*8;
        bf16x8 a;
#pragma unroll
        for (int j = 0; j < 8; ++j){
            int k = k0 + j;
            float v = (k < 3) ? ((k == 0) ? d0 : ((k == 1) ? d1 : d2))
                              : ((k < 67) ? prow[k-3] : 0.f);
            a[j] = (short)f2bf(v);
        }
#pragma unroll
        for (int nt = 0; nt < 4; ++nt)
            acc[nt] = __builtin_amdgcn_mfma_f32_16x16x32_bf16(a, Bf[nt][s], acc[nt], 0, 0, 0);
    }
    // C/D: col=lane&15, row=quad*4+reg. Epilogue: bias, store, f32 stats partials.
#pragma unroll
    for (int nt = 0; nt < 4; ++nt){
        int c = nt*16 + l16;
        float bb = b0[c];
        float sps = 0.f, spq = 0.f;
#pragma unroll
        for (int reg = 0; reg < 4; ++reg){
            int rr = r0 + q*4 + reg;
            float h = acc[nt][reg] + bb;
            sps += h;
            spq = fmaf(h, h, spq);
            z0[(size_t)rr*64 + c] = f2bf(h);
        }
        S_s[wave*4 + q][c] = sps;
        S_q[wave*4 + q][c] = spq;
    }
    __syncthreads();
    int t = threadIdx.x;
    if (t < 64){
        double ss = 0.0, sq = 0.0;
#pragma unroll
        for (int i = 0; i < 16; ++i){ ss += (double)S_s[i][t]; sq += (double)S_q[i][t]; }
        int cp = blockIdx.x & (NCOPY-1);
        atomicAdd(&accumOut[cp*256 + t], ss);
        atomicAdd(&accumOut[cp*256 + 128 + t], sq);
    }
}

// ---------------------------------------------------------------- layer 1: inline BN-param + BN+relu+GEMM K=64 + fused stats
__global__ __launch_bounds__(256) void layer1_mfma(const uint16_t* __restrict__ zin,
                                                   const double* __restrict__ accumIn,
                                                   const float* __restrict__ g,
                                                   const float* __restrict__ be,
                                                   const uint16_t* __restrict__ wb,
                                                   const float* __restrict__ bias,
                                                   uint16_t* __restrict__ zout,
                                                   double* __restrict__ accumOut){
    constexpr int NT = 4;
    __shared__ float sc_l[64], sh_l[64];
    __shared__ float S_s[16][64], S_q[16][64];
    const int t = threadIdx.x;
    if (t < 64){
        double s = 0.0, qq = 0.0;
#pragma unroll
        for (int cp = 0; cp < NCOPY; ++cp){
            s  += accumIn[cp*256 + t];
            qq += accumIn[cp*256 + 128 + t];
        }
        double mean = s / (double)NROWS;
        double var  = qq / (double)NROWS - mean*mean;
        double rs = 1.0 / sqrt(var + 1e-5);
        double scv = (double)g[t] * rs;
        sc_l[t] = (float)scv;
        sh_l[t] = (float)((double)be[t] - mean*scv);
    }
    __syncthreads();

    const int wave = t >> 6, lane = t & 63;
    const int q = lane >> 4, l16 = lane & 15;
    const int r0 = blockIdx.x*64 + wave*16;

    bf16x8 Bf[NT][2];
#pragma unroll
    for (int nt = 0; nt < NT; ++nt)
#pragma unroll
        for (int s = 0; s < 2; ++s)
            Bf[nt][s] = load_bf8(wb + (nt*16 + l16)*64 + s*32 + q*8);

    float sc[2][8], sh[2][8];
#pragma unroll
    for (int s = 0; s < 2; ++s)
#pragma unroll
        for (int j = 0; j < 8; ++j){
            sc[s][j] = sc_l[s*32 + q*8 + j];
            sh[s][j] = sh_l[s*32 + q*8 + j];
        }

    f32x4 acc[NT];
#pragma unroll
    for (int nt = 0; nt < NT; ++nt) acc[nt] = (f32x4){0.f,0.f,0.f,0.f};

    const uint16_t* zr = zin + (size_t)(r0 + l16)*64;
#pragma unroll
    for (int s = 0; s < 2; ++s){
        uint4 u = *reinterpret_cast<const uint4*>(zr + s*32 + q*8);
        float h[8];
        h[0] = bf2f((uint16_t)(u.x & 0xFFFF)); h[1] = bf2f((uint16_t)(u.x >> 16));
        h[2] = bf2f((uint16_t)(u.y & 0xFFFF)); h[3] = bf2f((uint16_t)(u.y >> 16));
        h[4] = bf2f((uint16_t)(u.z & 0xFFFF)); h[5] = bf2f((uint16_t)(u.z >> 16));
        h[6] = bf2f((uint16_t)(u.w & 0xFFFF)); h[7] = bf2f((uint16_t)(u.w >> 16));
        bf16x8 a;
#pragma unroll
        for (int j = 0; j < 8; ++j){
            float v = fmaxf(fmaf(h[j], sc[s][j], sh[s][j]), 0.f);
            a[j] = (short)f2bf(v);
        }
#pragma unroll
        for (int nt = 0; nt < NT; ++nt)
            acc[nt] = __builtin_amdgcn_mfma_f32_16x16x32_bf16(a, Bf[nt][s], acc[nt], 0, 0, 0);
    }
#pragma unroll
    for (int nt = 0; nt < NT; ++nt){
        int c = nt*16 + l16;
        float bb = bias[c];
        float sps = 0.f, spq = 0.f;
#pragma unroll
        for (int reg = 0; reg < 4; ++reg){
            int rr = r0 + q*4 + reg;
            float h = acc[nt][reg] + bb;
            sps += h;
            spq = fmaf(h, h, spq);
            zout[(size_t)rr*64 + c] = f2bf(h);
        }
        S_s[wave*4 + q][c] = sps;
        S_q[wave*4 + q][c] = spq;
    }
    __syncthreads();
    if (t < 64){
        double ss = 0.0, sq = 0.0;
#pragma unroll
        for (int i = 0; i < 16; ++i){ ss += (double)S_s[i][t]; sq += (double)S_q[i][t]; }
        int cp = blockIdx.x & (NCOPY-1);
        atomicAdd(&accumOut[cp*256 + t], ss);
        atomicAdd(&accumOut[cp*256 + 128 + t], sq);
    }
}

// ---------------------------------------------------------------- layer 2: BN+relu+GEMM K=64 -> 128 + fused stats + fused max/min POOLING
// Pooling in f32 pre-BN space; final kernel applies BN and picks max/min by
// sign(scale). z2 (67 MB x2 traffic) is never materialized.
__global__ __launch_bounds__(256) void layer2_mfma(const uint16_t* __restrict__ zin,
                                                   const double* __restrict__ accumIn,
                                                   const float* __restrict__ g,
                                                   const float* __restrict__ be,
                                                   const uint16_t* __restrict__ wb,
                                                   const float* __restrict__ bias,
                                                   float2* __restrict__ pool,
                                                   double* __restrict__ accumOut){
    constexpr int NT = 8;
    __shared__ float sc_l[64], sh_l[64];
    __shared__ float S_s[16][128], S_q[16][128];
    __shared__ float P_mx[16][128], P_mn[16][128];
    const int t = threadIdx.x;
    if (t < 64){
        double s = 0.0, qq = 0.0;
#pragma unroll
        for (int cp = 0; cp < NCOPY; ++cp){
            s  += accumIn[cp*256 + t];
            qq += accumIn[cp*256 + 128 + t];
        }
        double mean = s / (double)NROWS;
        double var  = qq / (double)NROWS - mean*mean;
        double rs = 1.0 / sqrt(var + 1e-5);
        double scv = (double)g[t] * rs;
        sc_l[t] = (float)scv;
        sh_l[t] = (float)((double)be[t] - mean*scv);
    }
    __syncthreads();

    const int wave = t >> 6, lane = t & 63;
    const int q = lane >> 4, l16 = lane & 15;
    const int r0 = blockIdx.x*64 + wave*16;

    bf16x8 Bf[NT][2];
#pragma unroll
    for (int nt = 0; nt < NT; ++nt)
#pragma unroll
        for (int s = 0; s < 2; ++s)
            Bf[nt][s] = load_bf8(wb + (nt*16 + l16)*64 + s*32 + q*8);

    float sc[2][8], sh[2][8];
#pragma unroll
    for (int s = 0; s < 2; ++s)
#pragma unroll
        for (int j = 0; j < 8; ++j){
            sc[s][j] = sc_l[s*32 + q*8 + j];
            sh[s][j] = sh_l[s*32 + q*8 + j];
        }

    f32x4 acc[NT];
#pragma unroll
    for (int nt = 0; nt < NT; ++nt) acc[nt] = (f32x4){0.f,0.f,0.f,0.f};

    const uint16_t* zr = zin + (size_t)(r0 + l16)*64;
#pragma unroll
    for (int s = 0; s < 2; ++s){
        uint4 u = *reinterpret_cast<const uint4*>(zr + s*32 + q*8);
        float h[8];
        h[0] = bf2f((uint16_t)(u.x & 0xFFFF)); h[1] = bf2f((uint16_t)(u.x >> 16));
        h[2] = bf2f((uint16_t)(u.y & 0xFFFF)); h[3] = bf2f((uint16_t)(u.y >> 16));
        h[4] = bf2f((uint16_t)(u.z & 0xFFFF)); h[5] = bf2f((uint16_t)(u.z >> 16));
        h[6] = bf2f((uint16_t)(u.w & 0xFFFF)); h[7] = bf2f((uint16_t)(u.w >> 16));
        bf16x8 a;
#pragma unroll
        for (int j = 0; j < 8; ++j){
            float v = fmaxf(fmaf(h[j], sc[s][j], sh[s][j]), 0.f);
            a[j] = (short)f2bf(v);
        }
#pragma unroll
        for (int nt = 0; nt < NT; ++nt)
            acc[nt] = __builtin_amdgcn_mfma_f32_16x16x32_bf16(a, Bf[nt][s], acc[nt], 0, 0, 0);
    }
#pragma unroll
    for (int nt = 0; nt < NT; ++nt){
        int c = nt*16 + l16;
        float bb = bias[c];
        float sps = 0.f, spq = 0.f;
        float mx = -1e30f, mn = 1e30f;
#pragma unroll
        for (int reg = 0; reg < 4; ++reg){
            float h = acc[nt][reg] + bb;
            sps += h;
            spq = fmaf(h, h, spq);
            mx = fmaxf(mx, h);
            mn = fminf(mn, h);
        }
        S_s[wave*4 + q][c] = sps;
        S_q[wave*4 + q][c] = spq;
        P_mx[wave*4 + q][c] = mx;
        P_mn[wave*4 + q][c] = mn;
    }
    __syncthreads();
    if (t < 128){
        double ss = 0.0, sq = 0.0;
#pragma unroll
        for (int i = 0; i < 16; ++i){ ss += (double)S_s[i][t]; sq += (double)S_q[i][t]; }
        int cp = blockIdx.x & (NCOPY-1);
        atomicAdd(&accumOut[cp*256 + t], ss);
        atomicAdd(&accumOut[cp*256 + 128 + t], sq);
    }
    // pooling: block covers 2 groups of 32 rows (= 2 (b,s) cells)
    {
        int gidx = t >> 7;          // 0..1
        int c = t & 127;
        float mx = -1e30f, mn = 1e30f;
#pragma unroll
        for (int i = 0; i < 8; ++i){
            mx = fmaxf(mx, P_mx[gidx*8 + i][c]);
            mn = fminf(mn, P_mn[gidx*8 + i][c]);
        }
        pool[(size_t)(blockIdx.x*2 + gidx)*128 + c] = make_float2(mx, mn);
    }
}

// ---------------------------------------------------------------- final: inline BN-param + select max/min by sign(scale) + BN + relu + transpose
__global__ __launch_bounds__(256) void final_kernel(const float2* __restrict__ pool,
                                                    const double* __restrict__ accumIn,
                                                    const float* __restrict__ g,
                                                    const float* __restrict__ be,
                                                    float* __restrict__ out){
    __shared__ float sc_l[128], sh_l[128];
    const int t0 = threadIdx.x;
    if (t0 < 128){
        double s = 0.0, qq = 0.0;
#pragma unroll
        for (int cp = 0; cp < NCOPY; ++cp){
            s  += accumIn[cp*256 + t0];
            qq += accumIn[cp*256 + 128 + t0];
        }
        double mean = s / (double)NROWS;
        double var  = qq / (double)NROWS - mean*mean;
        double rs = 1.0 / sqrt(var + 1e-5);
        double scv = (double)g[t0] * rs;
        sc_l[t0] = (float)scv;
        sh_l[t0] = (float)((double)be[t0] - mean*scv);
    }
    __syncthreads();

    int t = blockIdx.x*256 + threadIdx.x;   // 1048576 == pool linear index
    int o = t & 127;
    int s = (t >> 7) & 1023;
    int b = t >> 17;
    float2 p = pool[t];
    float sc = sc_l[o], sh = sh_l[o];
    float zsel = (sc >= 0.f) ? p.x : p.y;
    float y = fmaxf(fmaf(zsel, sc, sh), 0.f);
    out[24576 + ((size_t)b << 17) + ((size_t)o << 10) + s] = y;
}

// ---------------------------------------------------------------- launch
extern "C" void kernel_launch(void* const* d_in, const int* in_sizes, int n_in,
                              void* d_out, int out_size, void* d_ws, size_t ws_size,
                              hipStream_t stream) {
    const float* xyz = (const float*)d_in[0];
    const float* pts = (const float*)d_in[1];
    const float* w0  = (const float*)d_in[2];
    const float* b0  = (const float*)d_in[3];
    const float* g0  = (const float*)d_in[4];
    const float* be0 = (const float*)d_in[5];
    const float* w1  = (const float*)d_in[6];
    const float* b1  = (const float*)d_in[7];
    const float* g1  = (const float*)d_in[8];
    const float* be1 = (const float*)d_in[9];
    const float* w2  = (const float*)d_in[10];
    const float* b2  = (const float*)d_in[11];
    const float* g2  = (const float*)d_in[12];
    const float* be2 = (const float*)d_in[13];
    float* out = (float*)d_out;

    char* ws = (char*)d_ws;
    // accum: 3 layers x NCOPY x 256 doubles = 196608 B
    double*   accum0 = (double*)(ws + 0);
    double*   accum1 = (double*)(ws + 65536);
    double*   accum2 = (double*)(ws + 131072);
    uint16_t* w0b    = (uint16_t*)(ws + 196608);    // 12288 B
    uint16_t* w1b    = (uint16_t*)(ws + 208896);    // 8192 B
    uint16_t* w2b    = (uint16_t*)(ws + 217088);    // 16384 B
    uint16_t* z0     = (uint16_t*)(ws + 262144);    // 33554432 B
    uint16_t* z1     = (uint16_t*)(ws + 33816576);  // 33554432 B
    float2*   pool   = (float2*)  (ws + 67371008);  // 8388608 B
    int*      idx    = (int*)     (ws + 75759616);  // 1048576 B -> ends 76808192

    prep_kernel<<<32, 256, 0, stream>>>(w0, w1, w2, w0b, w1b, w2b, accum0);
    fps_kernel<<<NB, 256, 0, stream>>>(xyz, out);
    qball_kernel<<<2048, 256, 0, stream>>>(xyz, out, idx);
    layer0_mfma<<<4096, 256, 0, stream>>>(xyz, pts, idx, out, w0b, b0, z0, accum0);
    layer1_mfma<<<4096, 256, 0, stream>>>(z0, accum0, g0, be0, w1b, b1, z1, accum1);
    layer2_mfma<<<4096, 256, 0, stream>>>(z1, accum1, g1, be1, w2b, b2, pool, accum2);
    final_kernel<<<4096, 256, 0, stream>>>(pool, accum2, g2, be2, out);
}